// Round 8
// baseline (604.368 us; speedup 1.0000x reference)
//
#include <hip/hip_runtime.h>

// RGCN embedding, MI355X.  R17: relation-chunked LLC-resident pipeline.
// R16 proved producer/consumer coupling through LLC: nt stores on gemm1 pushed
// edge1csr FETCH to 205MB (full xw) -> xw gather lives off LLC hits, but
// xw=200MB thrashes.  Fix: chunk R into 4x8 rels.  Per chunk: gemm1c writes
// xwc [N_PAD][256] bf16 = 51.2MB (LLC-resident, reused in place across
// chunks -> no HBM roundtrip), edge1c consumes it from LLC and accumulates
// hidden1f (f32, 12.8MB).  Layer2 same with zc [N_PAD][128] = 25.6MB.
// kscatter2 now sorts each node's edges BY RELATION (has the (node,rel) hist
// already) and emits rowptrC[f][4] chunk offsets -> each edge pass touches
// only its chunk's edges.  nt stores reverted.
#define N_NODES 100000
#define N_PAD   100096
#define E_EDGES 3200000
#define NB      392            // buckets of 256 nodes
#define BCAP    12288
#define EPB     8192           // edges per kbinA block (32/thread)

typedef float f32x4 __attribute__((ext_vector_type(4)));
typedef __bf16 bf16x8 __attribute__((ext_vector_type(8)));

__device__ __forceinline__ float b2f(unsigned int u) {
    union { unsigned int i; float f; } x; x.i = u << 16; return x.f;
}
__device__ __forceinline__ unsigned short f2b(float f) {
    union { float f; unsigned int i; } x; x.f = f;
    unsigned int u = x.i + 0x7FFFu + ((x.i >> 16) & 1u);
    return (unsigned short)(u >> 16);
}
// pack 2 f32 -> 2 bf16 (RNE), lo in bits[15:0]
__device__ __forceinline__ unsigned int cvt2(float lo, float hi) {
    unsigned int r;
    asm("v_cvt_pk_bf16_f32 %0, %1, %2" : "=v"(r) : "v"(lo), "v"(hi));
    return r;
}

__global__ __launch_bounds__(256) void kcur(int* __restrict__ gCursor) {
    int id = blockIdx.x * 256 + threadIdx.x;
    if (id < NB) gCursor[id] = id * BCAP;
}

// emb f32 -> bf16, padded to N_PAD rows (pad = 0)
__global__ __launch_bounds__(256) void kemb(const float* __restrict__ emb,
                                            unsigned short* __restrict__ embb) {
    int id = blockIdx.x * 256 + threadIdx.x;
    if (id >= N_PAD * 128 / 8) return;
    size_t base = (size_t)id * 8;
    ushort4 o0 = {0, 0, 0, 0}, o1 = {0, 0, 0, 0};
    if (base < (size_t)N_NODES * 128) {
        float4 v0 = *(const float4*)(emb + base);
        float4 v1 = *(const float4*)(emb + base + 4);
        o0.x = f2b(v0.x); o0.y = f2b(v0.y); o0.z = f2b(v0.z); o0.w = f2b(v0.w);
        o1.x = f2b(v1.x); o1.y = f2b(v1.y); o1.z = f2b(v1.z); o1.w = f2b(v1.w);
    }
    *(ushort4*)(embb + base) = o0;
    *(ushort4*)(embb + base + 4) = o1;
}

// w1T[j][k] = sum_b comps1[r,b]*bases1[b,k,h], j=r*32+h  (bf16, [1024][128])
__global__ __launch_bounds__(256) void kw1(const float* __restrict__ comps1,
                                           const float* __restrict__ bases1,
                                           unsigned short* __restrict__ w1T) {
    int id = blockIdx.x * 256 + threadIdx.x;
    if (id >= 1024 * 128) return;
    int k = id & 127, j = id >> 7;
    int r = j >> 5, h = j & 31;
    float s = 0.f;
#pragma unroll
    for (int b = 0; b < 16; b++)
        s += comps1[r * 16 + b] * bases1[b * 4096 + k * 32 + h];
    w1T[(size_t)j * 128 + k] = f2b(s);
}

// w2T[j2][h] = sum_b comps2[r,b]*bases2[b,h,c], j2=r*16+c  (bf16, [512][32])
__global__ __launch_bounds__(256) void kw2(const float* __restrict__ comps2,
                                           const float* __restrict__ bases2,
                                           unsigned short* __restrict__ w2T) {
    int id = blockIdx.x * 256 + threadIdx.x;
    if (id >= 512 * 32) return;
    int h = id & 31, j = id >> 5;
    int r = j >> 4, c = j & 15;
    float s = 0.f;
#pragma unroll
    for (int b = 0; b < 16; b++)
        s += comps2[r * 16 + b] * bases2[b * 512 + h * 16 + c];
    w2T[(size_t)j * 32 + h] = f2b(s);
}

// Single-pass in-block counting sort by bucket (fr>>8).
// word=(frlo<<22)|(rel<<17)|to.  Per-bucket runs flushed contiguously.
__global__ __launch_bounds__(256) void kbinA(const int* __restrict__ rel,
                                             const int* __restrict__ fr,
                                             const int* __restrict__ to,
                                             int* __restrict__ gCursor,
                                             unsigned int* __restrict__ stage) {
    __shared__ int cnt[NB];
    __shared__ int lexcl[NB + 1];
    __shared__ int sdelta[NB];
    __shared__ int sa[512], sb_[512];
    __shared__ unsigned int sortbuf[EPB];
    int tid = threadIdx.x;
    int g40 = blockIdx.x * (EPB / 4);          // int4-group base
    unsigned int w_[32];
    int bk[32];
    for (int i = tid; i < NB; i += 256) cnt[i] = 0;
    __syncthreads();
    // load 32 edges into registers, LDS histogram
#pragma unroll
    for (int i = 0; i < 8; i++) {
        int g4 = g40 + i * 256 + tid;
        if (g4 < E_EDGES / 4) {
            int4 f4 = ((const int4*)fr)[g4];
            int4 r4 = ((const int4*)rel)[g4];
            int4 t4 = ((const int4*)to)[g4];
            int fa[4] = {f4.x, f4.y, f4.z, f4.w};
            int ra[4] = {r4.x, r4.y, r4.z, r4.w};
            int ta[4] = {t4.x, t4.y, t4.z, t4.w};
#pragma unroll
            for (int u = 0; u < 4; u++) {
                int b = fa[u] >> 8;
                w_[i * 4 + u] = ((unsigned int)(fa[u] & 255) << 22) |
                                ((unsigned int)ra[u] << 17) | (unsigned int)ta[u];
                bk[i * 4 + u] = b;
                atomicAdd(&cnt[b], 1);
            }
        } else {
#pragma unroll
            for (int u = 0; u < 4; u++) bk[i * 4 + u] = -1;
        }
    }
    __syncthreads();
    // inclusive scan of cnt[0..NB) over padded 512 domain (256 thr x 2 elem)
    sa[tid] = (tid < NB) ? cnt[tid] : 0;
    sa[tid + 256] = (tid + 256 < NB) ? cnt[tid + 256] : 0;
    __syncthreads();
    int* src = sa; int* dst = sb_;
    for (int ofs = 1; ofs < 512; ofs <<= 1) {
        int x0 = src[tid];
        if (tid >= ofs) x0 += src[tid - ofs];
        int x1 = src[tid + 256] + src[tid + 256 - ofs];
        __syncthreads();
        dst[tid] = x0; dst[tid + 256] = x1;
        __syncthreads();
        int* tmp = src; src = dst; dst = tmp;
    }
    // reserve global ranges, build local offsets
    for (int b = tid; b < NB; b += 256) {
        int c = cnt[b];
        int lex = src[b] - c;
        lexcl[b] = lex;
        int gb = 0;
        if (c) gb = atomicAdd(&gCursor[b], c);
        sdelta[b] = gb - lex;
        cnt[b] = 0;                       // reuse as rank counter
    }
    if (tid == 0) lexcl[NB] = src[NB - 1];
    __syncthreads();
    // rank-scatter into LDS sorted buffer
#pragma unroll
    for (int i = 0; i < 32; i++) {
        if (bk[i] >= 0) {
            int rank = atomicAdd(&cnt[bk[i]], 1);
            sortbuf[lexcl[bk[i]] + rank] = w_[i];
        }
    }
    __syncthreads();
    // flush per-bucket contiguous runs
    int wv = tid >> 6, lane = tid & 63;
    for (int b = wv; b < NB; b += 4) {
        int s = lexcl[b], e = lexcl[b + 1];
        int d = sdelta[b];
        for (int i = s + lane; i < e; i += 64)
            stage[d + i] = sortbuf[i];
    }
}

// exclusive scan of bucket counts -> bucketBase
__global__ __launch_bounds__(512) void kscan(const int* __restrict__ gCursor,
                                             int* __restrict__ bucketBase) {
    __shared__ int a[512], b[512];
    int t = threadIdx.x;
    int v = (t < NB) ? (gCursor[t] - t * BCAP) : 0;
    a[t] = v;
    __syncthreads();
    int* src = a; int* dst = b;
    for (int ofs = 1; ofs < 512; ofs <<= 1) {
        int x = src[t];
        if (t >= ofs) x += src[t - ofs];
        __syncthreads();
        dst[t] = x;
        __syncthreads();
        int* tmp = src; src = dst; dst = tmp;
    }
    if (t < NB) bucketBase[t] = src[t] - v;
}

// Per-bucket: (node,rel)-hist -> per-node rel prefix -> rowptr + rowptrC
// (chunk starts); scatter packed = (deg<<22)|(rel<<17)|to SORTED BY (node,rel).
__global__ __launch_bounds__(256) void kscatter2(const unsigned int* __restrict__ stage,
                                                 const int* __restrict__ gCursor,
                                                 const int* __restrict__ bucketBase,
                                                 int* __restrict__ rowptr,
                                                 int* __restrict__ rowptrC,
                                                 unsigned int* __restrict__ packed) {
    __shared__ int hexcl[256], sa[256], sb[256];
    __shared__ int hist2[256 * 32];
    __shared__ int relx[256 * 33];
    int b = blockIdx.x, t = threadIdx.x;
    int nb = gCursor[b] - b * BCAP;
    int sbase = b * BCAP;
    int gbase = bucketBase[b];
    int nb4 = nb >> 2;
    for (int i = t; i < 256 * 32; i += 256) hist2[i] = 0;
    __syncthreads();
    // (node,rel) histogram
    for (int i4 = t; i4 < nb4; i4 += 256) {
        uint4 p4 = ((const uint4*)(stage + sbase))[i4];
        unsigned int pa[4] = {p4.x, p4.y, p4.z, p4.w};
#pragma unroll
        for (int u = 0; u < 4; u++)
            atomicAdd(&hist2[((pa[u] >> 22) << 5) | ((pa[u] >> 17) & 31)], 1);
    }
    for (int i = (nb4 << 2) + t; i < nb; i += 256) {
        unsigned int pk = stage[sbase + i];
        atomicAdd(&hist2[((pk >> 22) << 5) | ((pk >> 17) & 31)], 1);
    }
    __syncthreads();
    // per-node rel prefix (thread t owns node t)
    int s = 0;
#pragma unroll
    for (int r = 0; r < 32; r++) {
        relx[t * 33 + r] = s;
        s += hist2[(t << 5) | r];
    }
    relx[t * 33 + 32] = s;
    // node-total scan -> hexcl / rowptr / rowptrC
    sa[t] = s;
    __syncthreads();
    int* src = sa; int* dst = sb;
    for (int ofs = 1; ofs < 256; ofs <<= 1) {
        int x = src[t];
        if (t >= ofs) x += src[t - ofs];
        __syncthreads();
        dst[t] = x;
        __syncthreads();
        int* tmp = src; src = dst; dst = tmp;
    }
    int excl = src[t] - s;
    hexcl[t] = excl;
    int gnode = b * 256 + t;
    rowptr[gnode] = gbase + excl;
#pragma unroll
    for (int c = 0; c < 4; c++)
        rowptrC[gnode * 4 + c] = gbase + excl + relx[t * 33 + c * 8];
    __syncthreads();
    // reuse hist2 as rank counters
    for (int i = t; i < 256 * 32; i += 256) hist2[i] = 0;
    __syncthreads();
    // scatter, rel-sorted within node
    for (int i4 = t; i4 < nb4; i4 += 256) {
        uint4 p4 = ((const uint4*)(stage + sbase))[i4];
        unsigned int pa[4] = {p4.x, p4.y, p4.z, p4.w};
#pragma unroll
        for (int u = 0; u < 4; u++) {
            int frlo = pa[u] >> 22, r = (pa[u] >> 17) & 31;
            int rank = atomicAdd(&hist2[(frlo << 5) | r], 1);
            int dg = min(relx[frlo * 33 + r + 1] - relx[frlo * 33 + r], 1023);
            packed[gbase + hexcl[frlo] + relx[frlo * 33 + r] + rank] =
                ((unsigned int)dg << 22) | (pa[u] & 0x3FFFFFu);
        }
    }
    for (int i = (nb4 << 2) + t; i < nb; i += 256) {
        unsigned int pk = stage[sbase + i];
        int frlo = pk >> 22, r = (pk >> 17) & 31;
        int rank = atomicAdd(&hist2[(frlo << 5) | r], 1);
        int dg = min(relx[frlo * 33 + r + 1] - relx[frlo * 33 + r], 1023);
        packed[gbase + hexcl[frlo] + relx[frlo * 33 + r] + rank] =
            ((unsigned int)dg << 22) | (pk & 0x3FFFFFu);
    }
}

// GEMM1 chunk: xwc[m][j] = sum_k embb[m][k]*w1Tc[j][k], j in [0,256) (8 rels).
// Block: 4 waves share 16 rows, each wave owns 64 cols; XCD-local A-slabs;
// ping-pong LDS tile; merged 512B-contiguous row stores (whole chunk row).
__global__ __launch_bounds__(256) void gemm1c(const unsigned short* __restrict__ embb,
                                              const unsigned short* __restrict__ w1Tc,
                                              unsigned short* __restrict__ xwc) {
    __shared__ unsigned short tile[2][16 * 260];
    int id = blockIdx.x;
    int xcd = id & 7, mgh = id >> 3;           // mgh in [0,49)
    int mg = mgh * 8 + xcd;                    // [0,392)
    int mrow0 = mg * 256;
    if (mrow0 >= N_PAD) return;                // mg=391 empty
    int lane = threadIdx.x & 63, wave = threadIdx.x >> 6;
    int m_ = lane & 15, q = lane >> 4;
    bf16x8 B[4][4];
    const unsigned short* Bbase = w1Tc + (size_t)(wave * 64 + m_) * 128 + q * 8;
#pragma unroll
    for (int j = 0; j < 4; j++)
#pragma unroll
        for (int k0 = 0; k0 < 4; k0++)
            B[j][k0] = *(const bf16x8*)(Bbase + j * 16 * 128 + k0 * 32);
    const unsigned short* Abase = embb + (size_t)(mrow0 + m_) * 128 + q * 8;
    bf16x8 a0[4], a1[4];
#pragma unroll
    for (int k0 = 0; k0 < 4; k0++)
        a0[k0] = *(const bf16x8*)(Abase + k0 * 32);
#pragma unroll
    for (int t = 0; t < 16; t++) {
        int m0 = mrow0 + t * 16;
        unsigned short* tw = tile[t & 1];
        bf16x8* acur = (t & 1) ? a1 : a0;
        bf16x8* anext = (t & 1) ? a0 : a1;
        if (t < 15) {
#pragma unroll
            for (int k0 = 0; k0 < 4; k0++)
                anext[k0] = *(const bf16x8*)(Abase + (size_t)(t + 1) * 16 * 128 + k0 * 32);
        }
        f32x4 acc[4] = {};
#pragma unroll
        for (int k0 = 0; k0 < 4; k0++)
#pragma unroll
            for (int j = 0; j < 4; j++)
                acc[j] = __builtin_amdgcn_mfma_f32_16x16x32_bf16(B[j][k0], acur[k0], acc[j], 0, 0, 0);
#pragma unroll
        for (int jj = 0; jj < 4; jj++) {
            uint2 s;
            s.x = cvt2(acc[jj][0], acc[jj][1]);
            s.y = cvt2(acc[jj][2], acc[jj][3]);
            *(uint2*)(tw + m_ * 260 + wave * 64 + jj * 16 + q * 4) = s;
        }
        __syncthreads();
#pragma unroll
        for (int half = 0; half < 2; half++) {
            int idx = threadIdx.x + half * 256;
            int row = idx >> 5, c16 = idx & 31;
            uint4 v = *(const uint4*)(tw + row * 260 + c16 * 8);
            int grow = m0 + row;
            if (grow < N_NODES)
                *(uint4*)(xwc + (size_t)grow * 256 + c16 * 8) = v;
        }
    }
}

// edge1 chunk: gather xwc (LLC-resident) over this chunk's edges only
// (rel-sorted CSR), accumulate hidden1f; final chunk applies bias+relu -> h1b.
__global__ __launch_bounds__(256) void edge1c(const unsigned int* __restrict__ packed,
                                              const int* __restrict__ rowptr,
                                              const int* __restrict__ rowptrC,
                                              const unsigned short* __restrict__ xwc,
                                              const float* __restrict__ bias1,
                                              float* __restrict__ h1f,
                                              unsigned short* __restrict__ h1b,
                                              int ch) {
    __shared__ unsigned int ebuf[4 * 64];
    __shared__ float vbuf[4 * 64];
    int wave = threadIdx.x >> 6, lane = threadIdx.x & 63;
    int f = blockIdx.x * 4 + wave;
    if (f >= N_NODES) return;
    int s = rowptrC[f * 4 + ch];
    int e_end = (ch == 3) ? rowptr[f + 1] : rowptrC[f * 4 + ch + 1];
    int k = e_end - s;
    int sub = lane & 7, p = lane >> 3;
    f32x4 acc = {0.f, 0.f, 0.f, 0.f};
    for (int base = 0; base < k; base += 64) {
        int e = base + lane;
        if (e < k) {
            unsigned int pk = packed[s + e];
            ebuf[wave * 64 + lane] = pk;
            vbuf[wave * 64 + lane] = 1.0f / (float)(pk >> 22);
        }
        int cnum = min(64, k - base);
        int nst = (cnum + 7) >> 3;
#pragma unroll 4
        for (int i = 0; i < nst; i++) {
            int ei = (i << 3) + p;
            if (ei < cnum) {
                unsigned int pk = ebuf[wave * 64 + ei];
                float v = vbuf[wave * 64 + ei];
                int t_ = pk & 0x1FFFF, r7 = (pk >> 17) & 7;
                ushort4 raw = *(const ushort4*)(xwc + (size_t)t_ * 256 + (r7 << 5) + (sub << 2));
                acc.x += v * b2f(raw.x); acc.y += v * b2f(raw.y);
                acc.z += v * b2f(raw.z); acc.w += v * b2f(raw.w);
            }
        }
    }
#pragma unroll
    for (int ofs = 8; ofs < 64; ofs <<= 1) {
        acc.x += __shfl_xor(acc.x, ofs, 64);
        acc.y += __shfl_xor(acc.y, ofs, 64);
        acc.z += __shfl_xor(acc.z, ofs, 64);
        acc.w += __shfl_xor(acc.w, ofs, 64);
    }
    if (p == 0) {
        int h = sub << 2;
        if (ch == 0) {
            float4 o = {acc.x, acc.y, acc.z, acc.w};
            *(float4*)(h1f + (size_t)f * 32 + h) = o;
        } else {
            float4 old = *(const float4*)(h1f + (size_t)f * 32 + h);
            float sx = old.x + acc.x, sy = old.y + acc.y;
            float sz = old.z + acc.z, sw = old.w + acc.w;
            if (ch < 3) {
                float4 o = {sx, sy, sz, sw};
                *(float4*)(h1f + (size_t)f * 32 + h) = o;
            } else {
                ushort4 o;
                o.x = f2b(fmaxf(sx + bias1[h + 0], 0.f));
                o.y = f2b(fmaxf(sy + bias1[h + 1], 0.f));
                o.z = f2b(fmaxf(sz + bias1[h + 2], 0.f));
                o.w = f2b(fmaxf(sw + bias1[h + 3], 0.f));
                *(ushort4*)(h1b + (size_t)f * 32 + h) = o;
            }
        }
    }
}

// GEMM2 chunk: zc[m][j] = sum_h h1b[m][h]*w2Tc[j][h], j in [0,128) (8 rels).
__global__ __launch_bounds__(256) void gemm2c(const unsigned short* __restrict__ h1b,
                                              const unsigned short* __restrict__ w2Tc,
                                              unsigned short* __restrict__ zc) {
    __shared__ unsigned short ldsT[4 * 16 * 136];
    int id = blockIdx.x;
    int xcd = id & 7, w = id >> 3;
    int bn = w & 1, mgl = w >> 1;              // bn in [0,2), mgl in [0,13)
    int mg = mgl * 8 + xcd;
    if (mg >= 98) return;
    int lane = threadIdx.x & 63, wave = threadIdx.x >> 6;
    int m_ = lane & 15, q = lane >> 4;
    unsigned short* tw = &ldsT[wave * 16 * 136];
    bf16x8 B[4];
    const unsigned short* Bbase = w2Tc + (size_t)(bn * 64 + m_) * 32 + q * 8;
#pragma unroll
    for (int j = 0; j < 4; j++)
        B[j] = *(const bf16x8*)(Bbase + j * 16 * 32);
    int mrow0 = mg * 1024 + wave * 32;
    const unsigned short* Abase = h1b + (size_t)(mrow0 + m_) * 32 + q * 8;
    bf16x8 a0[2], a1[2];
    if (mrow0 < N_PAD) {
        a0[0] = *(const bf16x8*)(Abase);
        a0[1] = *(const bf16x8*)(Abase + 16 * 32);
    }
#pragma unroll
    for (int t = 0; t < 8; t++) {
        int m0 = mrow0 + t * 128;
        if (m0 >= N_PAD) break;
        bf16x8* acur = (t & 1) ? a1 : a0;
        bf16x8* anext = (t & 1) ? a0 : a1;
        if (t < 7 && m0 + 128 < N_PAD) {
            anext[0] = *(const bf16x8*)(Abase + (size_t)(t + 1) * 128 * 32);
            anext[1] = *(const bf16x8*)(Abase + (size_t)(t + 1) * 128 * 32 + 16 * 32);
        }
        f32x4 acc[2][4] = {};
#pragma unroll
        for (int i = 0; i < 2; i++)
#pragma unroll
            for (int j = 0; j < 4; j++)
                acc[i][j] = __builtin_amdgcn_mfma_f32_16x16x32_bf16(B[j], acur[i], acc[i][j], 0, 0, 0);
#pragma unroll
        for (int i = 0; i < 2; i++) {
#pragma unroll
            for (int jj = 0; jj < 4; jj++) {
                uint2 s;
                s.x = cvt2(acc[i][jj][0], acc[i][jj][1]);
                s.y = cvt2(acc[i][jj][2], acc[i][jj][3]);
                *(uint2*)(tw + m_ * 136 + jj * 16 + q * 4) = s;
            }
            __asm__ volatile("s_waitcnt lgkmcnt(0)" ::: "memory");
#pragma unroll
            for (int ri = 0; ri < 2; ri++) {
                int row = (lane >> 3) + ri * 8;
                int c = lane & 7;
                uint4 v = *(const uint4*)(tw + row * 136 + c * 8);
                int grow = m0 + i * 16 + row;
                if (grow < N_NODES)
                    *(uint4*)(zc + (size_t)grow * 128 + bn * 64 + c * 8) = v;
            }
            __asm__ volatile("s_waitcnt lgkmcnt(0)" ::: "memory");
        }
    }
}

// edge2 chunk: gather zc (LLC-resident), accumulate into out (f32).
__global__ __launch_bounds__(256) void edge2c(const unsigned int* __restrict__ packed,
                                              const int* __restrict__ rowptr,
                                              const int* __restrict__ rowptrC,
                                              const unsigned short* __restrict__ zc,
                                              const float* __restrict__ bias2,
                                              float* __restrict__ out,
                                              int ch) {
    __shared__ unsigned int ebuf[4 * 64];
    __shared__ float vbuf[4 * 64];
    int wave = threadIdx.x >> 6, lane = threadIdx.x & 63;
    int f = blockIdx.x * 4 + wave;
    if (f >= N_NODES) return;
    int s = rowptrC[f * 4 + ch];
    int e_end = (ch == 3) ? rowptr[f + 1] : rowptrC[f * 4 + ch + 1];
    int k = e_end - s;
    int sub = lane & 3, p = lane >> 2;
    f32x4 acc = {0.f, 0.f, 0.f, 0.f};
    for (int base = 0; base < k; base += 64) {
        int e = base + lane;
        if (e < k) {
            unsigned int pk = packed[s + e];
            ebuf[wave * 64 + lane] = pk;
            vbuf[wave * 64 + lane] = 1.0f / (float)(pk >> 22);
        }
        int cnum = min(64, k - base);
        int nst = (cnum + 15) >> 4;
#pragma unroll 4
        for (int i = 0; i < nst; i++) {
            int ei = (i << 4) + p;
            if (ei < cnum) {
                unsigned int pk = ebuf[wave * 64 + ei];
                float v = vbuf[wave * 64 + ei];
                int t_ = pk & 0x1FFFF, r7 = (pk >> 17) & 7;
                ushort4 raw = *(const ushort4*)(zc + (size_t)t_ * 128 + (r7 << 4) + (sub << 2));
                acc.x += v * b2f(raw.x); acc.y += v * b2f(raw.y);
                acc.z += v * b2f(raw.z); acc.w += v * b2f(raw.w);
            }
        }
    }
#pragma unroll
    for (int ofs = 4; ofs < 64; ofs <<= 1) {
        acc.x += __shfl_xor(acc.x, ofs, 64);
        acc.y += __shfl_xor(acc.y, ofs, 64);
        acc.z += __shfl_xor(acc.z, ofs, 64);
        acc.w += __shfl_xor(acc.w, ofs, 64);
    }
    if (p == 0) {
        int c = sub << 2;
        float4 o;
        if (ch == 0) {
            o.x = acc.x + bias2[c + 0];
            o.y = acc.y + bias2[c + 1];
            o.z = acc.z + bias2[c + 2];
            o.w = acc.w + bias2[c + 3];
        } else {
            float4 old = *(const float4*)(out + (size_t)f * 16 + c);
            o.x = old.x + acc.x; o.y = old.y + acc.y;
            o.z = old.z + acc.z; o.w = old.w + acc.w;
        }
        *(float4*)(out + (size_t)f * 16 + c) = o;
    }
}

extern "C" void kernel_launch(void* const* d_in, const int* in_sizes, int n_in,
                              void* d_out, int out_size, void* d_ws, size_t ws_size,
                              hipStream_t stream) {
    (void)in_sizes; (void)n_in; (void)out_size; (void)ws_size;
    const float* emb    = (const float*)d_in[0];
    const float* comps1 = (const float*)d_in[1];
    const float* bases1 = (const float*)d_in[2];
    const float* comps2 = (const float*)d_in[3];
    const float* bases2 = (const float*)d_in[4];
    const float* bias1  = (const float*)d_in[5];
    const float* bias2  = (const float*)d_in[6];
    const int* rel = (const int*)d_in[7];
    const int* fr  = (const int*)d_in[8];
    const int* to  = (const int*)d_in[9];
    float* out = (float*)d_out;
    char* ws = (char*)d_ws;

    // workspace layout (bytes); total ~111.2 MB
    int* gCursor         = (int*)(ws);                        // 1,568
    int* bucketBase      = (int*)(ws + 2048);                 // 1,568
    int* rowptr          = (int*)(ws + 4096);                 // 401,412
    int* rowptrC         = (int*)(ws + 406528);               // 1,605,632
    unsigned int* packed = (unsigned int*)(ws + 2012160);     // 12,800,000
    unsigned short* h1b  = (unsigned short*)(ws + 14812160);  // 6,406,144 (N_PAD x 32)
    unsigned short* w1T  = (unsigned short*)(ws + 21218304);  // 262,144
    unsigned short* w2T  = (unsigned short*)(ws + 21480448);  // 32,768
    float* h1f           = (float*)(ws + 21513216);           // 12,800,000 (N x 32 f32)
    unsigned short* embb = (unsigned short*)(ws + 34313216);  // 25,624,576 (N_PAD x 128)
    unsigned short* xwc  = (unsigned short*)(ws + 59937792);  // 51,249,152 (N_PAD x 256)
    unsigned short* zc   = xwc;                 // alias: xwc dead before gemm2c
    unsigned int* stage  = (unsigned int*)xwc;  // alias: stage dead before gemm1c

    kcur<<<2, 256, 0, stream>>>(gCursor);
    kemb<<<6256, 256, 0, stream>>>(emb, embb);
    kw1<<<512, 256, 0, stream>>>(comps1, bases1, w1T);
    kw2<<<64, 256, 0, stream>>>(comps2, bases2, w2T);
    kbinA<<<(E_EDGES + EPB - 1) / EPB, 256, 0, stream>>>(rel, fr, to, gCursor, stage);
    kscan<<<1, 512, 0, stream>>>(gCursor, bucketBase);
    kscatter2<<<NB, 256, 0, stream>>>(stage, gCursor, bucketBase, rowptr, rowptrC, packed);
    for (int ch = 0; ch < 4; ch++) {
        gemm1c<<<392, 256, 0, stream>>>(embb, w1T + (size_t)ch * 256 * 128, xwc);
        edge1c<<<25000, 256, 0, stream>>>(packed, rowptr, rowptrC, xwc, bias1, h1f, h1b, ch);
    }
    for (int ch = 0; ch < 4; ch++) {
        gemm2c<<<208, 256, 0, stream>>>(h1b, w2T + (size_t)ch * 128 * 32, zc);
        edge2c<<<25000, 256, 0, stream>>>(packed, rowptr, rowptrC, zc, bias2, out, ch);
    }
}

// Round 9
// 470.525 us; speedup vs baseline: 1.2845x; 1.2845x over previous
//
#include <hip/hip_runtime.h>

// RGCN embedding, MI355X.  R18: consolidation.  R17 chunking regressed (604us:
// 8 edge passes x 25000 blocks of fixed overhead at ~8 edges/node/chunk) ->
// revert to R14 pipeline.  Surgical cuts on calibrated costs: (1) kemb deleted
// — embb was consumed only by gemm1; gemm1 now reads emb f32 directly with
// clamped rows + v_cvt_pk_bf16_f32 inline (same RNE, bit-identical);
// (2) kbinA EPB 8192->4096: sortbuf 32->16KB, LDS 42->~25KB -> 2x blocks/CU
// for a latency-bound kernel (occ 12.8%, all pipes idle).  Rest = R14 verbatim.
#define N_NODES 100000
#define N_PAD   100096
#define E_EDGES 3200000
#define NB      392            // buckets of 256 nodes
#define BCAP    12288
#define EPB     4096           // edges per kbinA block (16/thread)

typedef float f32x4 __attribute__((ext_vector_type(4)));
typedef __bf16 bf16x8 __attribute__((ext_vector_type(8)));

__device__ __forceinline__ float b2f(unsigned int u) {
    union { unsigned int i; float f; } x; x.i = u << 16; return x.f;
}
__device__ __forceinline__ unsigned short f2b(float f) {
    union { float f; unsigned int i; } x; x.f = f;
    unsigned int u = x.i + 0x7FFFu + ((x.i >> 16) & 1u);
    return (unsigned short)(u >> 16);
}
// pack 2 f32 -> 2 bf16 (RNE), lo in bits[15:0]
__device__ __forceinline__ unsigned int cvt2(float lo, float hi) {
    unsigned int r;
    asm("v_cvt_pk_bf16_f32 %0, %1, %2" : "=v"(r) : "v"(lo), "v"(hi));
    return r;
}

__global__ __launch_bounds__(256) void kcur(int* __restrict__ gCursor) {
    int id = blockIdx.x * 256 + threadIdx.x;
    if (id < NB) gCursor[id] = id * BCAP;
}

// w1T[j][k] = sum_b comps1[r,b]*bases1[b,k,h], j=r*32+h  (bf16, [1024][128])
__global__ __launch_bounds__(256) void kw1(const float* __restrict__ comps1,
                                           const float* __restrict__ bases1,
                                           unsigned short* __restrict__ w1T) {
    int id = blockIdx.x * 256 + threadIdx.x;
    if (id >= 1024 * 128) return;
    int k = id & 127, j = id >> 7;
    int r = j >> 5, h = j & 31;
    float s = 0.f;
#pragma unroll
    for (int b = 0; b < 16; b++)
        s += comps1[r * 16 + b] * bases1[b * 4096 + k * 32 + h];
    w1T[(size_t)j * 128 + k] = f2b(s);
}

// w2T[j2][h] = sum_b comps2[r,b]*bases2[b,h,c], j2=r*16+c  (bf16, [512][32])
__global__ __launch_bounds__(256) void kw2(const float* __restrict__ comps2,
                                           const float* __restrict__ bases2,
                                           unsigned short* __restrict__ w2T) {
    int id = blockIdx.x * 256 + threadIdx.x;
    if (id >= 512 * 32) return;
    int h = id & 31, j = id >> 5;
    int r = j >> 4, c = j & 15;
    float s = 0.f;
#pragma unroll
    for (int b = 0; b < 16; b++)
        s += comps2[r * 16 + b] * bases2[b * 512 + h * 16 + c];
    w2T[(size_t)j * 32 + h] = f2b(s);
}

// Single-pass in-block counting sort by bucket (fr>>8).  EPB=4096 (16/thread):
// sortbuf 16KB -> ~6 blocks/CU for this latency-bound kernel.
__global__ __launch_bounds__(256) void kbinA(const int* __restrict__ rel,
                                             const int* __restrict__ fr,
                                             const int* __restrict__ to,
                                             int* __restrict__ gCursor,
                                             unsigned int* __restrict__ stage) {
    __shared__ int cnt[NB];
    __shared__ int lexcl[NB + 1];
    __shared__ int sdelta[NB];
    __shared__ int sa[512], sb_[512];
    __shared__ unsigned int sortbuf[EPB];
    int tid = threadIdx.x;
    int g40 = blockIdx.x * (EPB / 4);          // int4-group base
    unsigned int w_[16];
    int bk[16];
    for (int i = tid; i < NB; i += 256) cnt[i] = 0;
    __syncthreads();
    // load 16 edges into registers, LDS histogram
#pragma unroll
    for (int i = 0; i < EPB / 1024; i++) {
        int g4 = g40 + i * 256 + tid;
        if (g4 < E_EDGES / 4) {
            int4 f4 = ((const int4*)fr)[g4];
            int4 r4 = ((const int4*)rel)[g4];
            int4 t4 = ((const int4*)to)[g4];
            int fa[4] = {f4.x, f4.y, f4.z, f4.w};
            int ra[4] = {r4.x, r4.y, r4.z, r4.w};
            int ta[4] = {t4.x, t4.y, t4.z, t4.w};
#pragma unroll
            for (int u = 0; u < 4; u++) {
                int b = fa[u] >> 8;
                w_[i * 4 + u] = ((unsigned int)(fa[u] & 255) << 22) |
                                ((unsigned int)ra[u] << 17) | (unsigned int)ta[u];
                bk[i * 4 + u] = b;
                atomicAdd(&cnt[b], 1);
            }
        } else {
#pragma unroll
            for (int u = 0; u < 4; u++) bk[i * 4 + u] = -1;
        }
    }
    __syncthreads();
    // inclusive scan of cnt[0..NB) over padded 512 domain (256 thr x 2 elem)
    sa[tid] = (tid < NB) ? cnt[tid] : 0;
    sa[tid + 256] = (tid + 256 < NB) ? cnt[tid + 256] : 0;
    __syncthreads();
    int* src = sa; int* dst = sb_;
    for (int ofs = 1; ofs < 512; ofs <<= 1) {
        int x0 = src[tid];
        if (tid >= ofs) x0 += src[tid - ofs];
        int x1 = src[tid + 256] + src[tid + 256 - ofs];
        __syncthreads();
        dst[tid] = x0; dst[tid + 256] = x1;
        __syncthreads();
        int* tmp = src; src = dst; dst = tmp;
    }
    // reserve global ranges, build local offsets
    for (int b = tid; b < NB; b += 256) {
        int c = cnt[b];
        int lex = src[b] - c;
        lexcl[b] = lex;
        int gb = 0;
        if (c) gb = atomicAdd(&gCursor[b], c);
        sdelta[b] = gb - lex;
        cnt[b] = 0;                       // reuse as rank counter
    }
    if (tid == 0) lexcl[NB] = src[NB - 1];
    __syncthreads();
    // rank-scatter into LDS sorted buffer
#pragma unroll
    for (int i = 0; i < 16; i++) {
        if (bk[i] >= 0) {
            int rank = atomicAdd(&cnt[bk[i]], 1);
            sortbuf[lexcl[bk[i]] + rank] = w_[i];
        }
    }
    __syncthreads();
    // flush per-bucket contiguous runs
    int wv = tid >> 6, lane = tid & 63;
    for (int b = wv; b < NB; b += 4) {
        int s = lexcl[b], e = lexcl[b + 1];
        int d = sdelta[b];
        for (int i = s + lane; i < e; i += 64)
            stage[d + i] = sortbuf[i];
    }
}

// exclusive scan of bucket counts -> bucketBase
__global__ __launch_bounds__(512) void kscan(const int* __restrict__ gCursor,
                                             int* __restrict__ bucketBase) {
    __shared__ int a[512], b[512];
    int t = threadIdx.x;
    int v = (t < NB) ? (gCursor[t] - t * BCAP) : 0;
    a[t] = v;
    __syncthreads();
    int* src = a; int* dst = b;
    for (int ofs = 1; ofs < 512; ofs <<= 1) {
        int x = src[t];
        if (t >= ofs) x += src[t - ofs];
        __syncthreads();
        dst[t] = x;
        __syncthreads();
        int* tmp = src; src = dst; dst = tmp;
    }
    if (t < NB) bucketBase[t] = src[t] - v;
}

// Per-bucket: LDS node-hist -> scan -> rowptr; (node,rel)-hist -> deg;
// scatter packed = (deg<<22)|(rel<<17)|to.  uint4 stage loads.
__global__ __launch_bounds__(256) void kscatter2(const unsigned int* __restrict__ stage,
                                                 const int* __restrict__ gCursor,
                                                 const int* __restrict__ bucketBase,
                                                 int* __restrict__ rowptr,
                                                 unsigned int* __restrict__ packed) {
    __shared__ int hist[256], hexcl[256], rk[256], sa[256], sb[256];
    __shared__ int hist2[256 * 32];
    int b = blockIdx.x, t = threadIdx.x;
    int nb = gCursor[b] - b * BCAP;
    int sbase = b * BCAP;
    int gbase = bucketBase[b];
    int nb4 = nb >> 2;
    hist[t] = 0; rk[t] = 0;
    for (int i = t; i < 256 * 32; i += 256) hist2[i] = 0;
    __syncthreads();
    for (int i4 = t; i4 < nb4; i4 += 256) {
        uint4 p4 = ((const uint4*)(stage + sbase))[i4];
        unsigned int pa[4] = {p4.x, p4.y, p4.z, p4.w};
#pragma unroll
        for (int u = 0; u < 4; u++) {
            atomicAdd(&hist[pa[u] >> 22], 1);
            atomicAdd(&hist2[((pa[u] >> 22) << 5) | ((pa[u] >> 17) & 31)], 1);
        }
    }
    for (int i = (nb4 << 2) + t; i < nb; i += 256) {
        unsigned int pk = stage[sbase + i];
        atomicAdd(&hist[pk >> 22], 1);
        atomicAdd(&hist2[((pk >> 22) << 5) | ((pk >> 17) & 31)], 1);
    }
    __syncthreads();
    int v = hist[t];
    sa[t] = v;
    __syncthreads();
    int* src = sa; int* dst = sb;
    for (int ofs = 1; ofs < 256; ofs <<= 1) {
        int x = src[t];
        if (t >= ofs) x += src[t - ofs];
        __syncthreads();
        dst[t] = x;
        __syncthreads();
        int* tmp = src; src = dst; dst = tmp;
    }
    int excl = src[t] - v;
    hexcl[t] = excl;
    rowptr[b * 256 + t] = gbase + excl;
    __syncthreads();
    for (int i4 = t; i4 < nb4; i4 += 256) {
        uint4 p4 = ((const uint4*)(stage + sbase))[i4];
        unsigned int pa[4] = {p4.x, p4.y, p4.z, p4.w};
#pragma unroll
        for (int u = 0; u < 4; u++) {
            int frlo = pa[u] >> 22;
            int rank = atomicAdd(&rk[frlo], 1);
            int dg = min(hist2[(frlo << 5) | ((pa[u] >> 17) & 31)], 1023);
            packed[gbase + hexcl[frlo] + rank] = ((unsigned int)dg << 22) | (pa[u] & 0x3FFFFFu);
        }
    }
    for (int i = (nb4 << 2) + t; i < nb; i += 256) {
        unsigned int pk = stage[sbase + i];
        int frlo = pk >> 22;
        int rank = atomicAdd(&rk[frlo], 1);
        int dg = min(hist2[(frlo << 5) | ((pk >> 17) & 31)], 1023);
        packed[gbase + hexcl[frlo] + rank] = ((unsigned int)dg << 22) | (pk & 0x3FFFFFu);
    }
}

// GEMM1 (row-shared block + merged wide epilogue, XCD-local, inline f32 A):
// xw[m][j] = sum_k emb[m][k]*w1T[j][k].  A read as f32 (clamped row for pad
// tail) and converted inline via v_cvt_pk_bf16_f32 (same RNE as old kemb).
__global__ __launch_bounds__(256) void gemm1(const float* __restrict__ emb,
                                             const unsigned short* __restrict__ w1T,
                                             unsigned short* __restrict__ xw) {
    __shared__ unsigned short tile[2][16 * 260];
    int id = blockIdx.x;
    int xcd = id & 7;
    int k_ = id >> 3;
    int bn4 = k_ & 3, mgh = k_ >> 2;           // mgh in [0,49)
    int mg = mgh * 8 + xcd;                    // [0,392)
    int mrow0 = mg * 256;
    if (mrow0 >= N_PAD) return;                // mg=391 empty
    int lane = threadIdx.x & 63, wave = threadIdx.x >> 6;
    int bn = bn4 * 4 + wave;
    int m_ = lane & 15, q = lane >> 4;
    bf16x8 B[4][4];
    const unsigned short* Bbase = w1T + (size_t)(bn * 64 + m_) * 128 + q * 8;
#pragma unroll
    for (int j = 0; j < 4; j++)
#pragma unroll
        for (int k0 = 0; k0 < 4; k0++)
            B[j][k0] = *(const bf16x8*)(Bbase + j * 16 * 128 + k0 * 32);
    bf16x8 a0[4], a1[4];
    // f32 A load with clamped row (pad rows read row N_NODES-1; outputs guarded)
#define LOADA(tt, dst)                                                         \
    {                                                                          \
        int row_ = mrow0 + (tt) * 16 + m_;                                     \
        row_ = (row_ < N_NODES) ? row_ : (N_NODES - 1);                        \
        const float* p_ = emb + (size_t)row_ * 128 + q * 8;                    \
        _Pragma("unroll")                                                      \
        for (int k0 = 0; k0 < 4; k0++) {                                       \
            float4 v0 = *(const float4*)(p_ + k0 * 32);                        \
            float4 v1 = *(const float4*)(p_ + k0 * 32 + 4);                    \
            union { unsigned int u[4]; bf16x8 v; } cv_;                        \
            cv_.u[0] = cvt2(v0.x, v0.y);                                       \
            cv_.u[1] = cvt2(v0.z, v0.w);                                       \
            cv_.u[2] = cvt2(v1.x, v1.y);                                       \
            cv_.u[3] = cvt2(v1.z, v1.w);                                       \
            (dst)[k0] = cv_.v;                                                 \
        }                                                                      \
    }
    LOADA(0, a0)
#pragma unroll
    for (int t = 0; t < 16; t++) {
        int m0 = mrow0 + t * 16;
        unsigned short* tw = tile[t & 1];
        bf16x8* acur = (t & 1) ? a1 : a0;
        bf16x8* anext = (t & 1) ? a0 : a1;
        if (t < 15) LOADA(t + 1, anext)
        f32x4 acc[4] = {};
#pragma unroll
        for (int k0 = 0; k0 < 4; k0++)
#pragma unroll
            for (int j = 0; j < 4; j++)
                acc[j] = __builtin_amdgcn_mfma_f32_16x16x32_bf16(B[j][k0], acur[k0], acc[j], 0, 0, 0);
        // pack: row m_, cols wave*64 + jj*16 + q*4 (+reg)
#pragma unroll
        for (int jj = 0; jj < 4; jj++) {
            uint2 s;
            s.x = cvt2(acc[jj][0], acc[jj][1]);
            s.y = cvt2(acc[jj][2], acc[jj][3]);
            *(uint2*)(tw + m_ * 260 + wave * 64 + jj * 16 + q * 4) = s;
        }
        __syncthreads();
        // merged store: 512 uint4 chunks (16 rows x 512B), 2 per thread
#pragma unroll
        for (int half = 0; half < 2; half++) {
            int idx = threadIdx.x + half * 256;
            int row = idx >> 5, c16 = idx & 31;
            uint4 v = *(const uint4*)(tw + row * 260 + c16 * 8);
            int grow = m0 + row;
            if (grow < N_NODES)
                *(uint4*)(xw + (size_t)grow * 1024 + bn4 * 256 + c16 * 8) = v;
        }
    }
#undef LOADA
}

// edge1csr: one wave per node, single pass (deg packed).  8 edges/instr.
__global__ __launch_bounds__(256) void edge1csr(const unsigned int* __restrict__ packed,
                                                const int* __restrict__ rowptr,
                                                const unsigned short* __restrict__ xw,
                                                const float* __restrict__ bias1,
                                                unsigned short* __restrict__ h1b) {
    __shared__ unsigned int ebuf[4 * 64];
    __shared__ float vbuf[4 * 64];
    int wave = threadIdx.x >> 6, lane = threadIdx.x & 63;
    int f = blockIdx.x * 4 + wave;
    if (f >= N_NODES) return;
    int s = rowptr[f], k = rowptr[f + 1] - s;
    int sub = lane & 7, p = lane >> 3;
    f32x4 acc = {0.f, 0.f, 0.f, 0.f};
    for (int base = 0; base < k; base += 64) {
        int e = base + lane;
        if (e < k) {
            unsigned int pk = packed[s + e];
            ebuf[wave * 64 + lane] = pk;
            vbuf[wave * 64 + lane] = 1.0f / (float)(pk >> 22);
        }
        int cnum = min(64, k - base);
        int nst = (cnum + 7) >> 3;
#pragma unroll 4
        for (int i = 0; i < nst; i++) {
            int ei = (i << 3) + p;
            if (ei < cnum) {
                unsigned int pk = ebuf[wave * 64 + ei];
                float v = vbuf[wave * 64 + ei];
                int t_ = pk & 0x1FFFF, r = (pk >> 17) & 31;
                ushort4 raw = *(const ushort4*)(xw + (size_t)t_ * 1024 + (r << 5) + (sub << 2));
                acc.x += v * b2f(raw.x); acc.y += v * b2f(raw.y);
                acc.z += v * b2f(raw.z); acc.w += v * b2f(raw.w);
            }
        }
    }
#pragma unroll
    for (int ofs = 8; ofs < 64; ofs <<= 1) {
        acc.x += __shfl_xor(acc.x, ofs, 64);
        acc.y += __shfl_xor(acc.y, ofs, 64);
        acc.z += __shfl_xor(acc.z, ofs, 64);
        acc.w += __shfl_xor(acc.w, ofs, 64);
    }
    if (p == 0) {
        int h = sub << 2;
        ushort4 o;
        o.x = f2b(fmaxf(acc.x + bias1[h + 0], 0.f));
        o.y = f2b(fmaxf(acc.y + bias1[h + 1], 0.f));
        o.z = f2b(fmaxf(acc.z + bias1[h + 2], 0.f));
        o.w = f2b(fmaxf(acc.w + bias1[h + 3], 0.f));
        *(ushort4*)(h1b + (size_t)f * 32 + h) = o;
    }
}

// GEMM2 (streaming-wave + LDS-pack epilogue, R11): z[m][j2] = sum_h h1b[m][h]*w2T[j2][h].
__global__ __launch_bounds__(256) void gemm2(const unsigned short* __restrict__ h1b,
                                             const unsigned short* __restrict__ w2T,
                                             unsigned short* __restrict__ z) {
    __shared__ unsigned short ldsT[4 * 16 * 136];
    int id = blockIdx.x;
    int xcd = id & 7, w = id >> 3;
    int bn = w & 7, mgl = w >> 3;
    int mg = mgl * 8 + xcd;
    if (mg >= 98) return;
    int lane = threadIdx.x & 63, wave = threadIdx.x >> 6;
    int m_ = lane & 15, q = lane >> 4;
    unsigned short* tw = &ldsT[wave * 16 * 136];
    bf16x8 B[4];
    const unsigned short* Bbase = w2T + (size_t)(bn * 64 + m_) * 32 + q * 8;
#pragma unroll
    for (int j = 0; j < 4; j++)
        B[j] = *(const bf16x8*)(Bbase + j * 16 * 32);
    int mrow0 = mg * 1024 + wave * 32;
    const unsigned short* Abase = h1b + (size_t)(mrow0 + m_) * 32 + q * 8;
    bf16x8 a0[2], a1[2];
    if (mrow0 < N_PAD) {
        a0[0] = *(const bf16x8*)(Abase);
        a0[1] = *(const bf16x8*)(Abase + 16 * 32);
    }
#pragma unroll
    for (int t = 0; t < 8; t++) {
        int m0 = mrow0 + t * 128;
        if (m0 >= N_PAD) break;
        bf16x8* acur = (t & 1) ? a1 : a0;
        bf16x8* anext = (t & 1) ? a0 : a1;
        if (t < 7 && m0 + 128 < N_PAD) {
            anext[0] = *(const bf16x8*)(Abase + (size_t)(t + 1) * 128 * 32);
            anext[1] = *(const bf16x8*)(Abase + (size_t)(t + 1) * 128 * 32 + 16 * 32);
        }
        f32x4 acc[2][4] = {};
#pragma unroll
        for (int i = 0; i < 2; i++)
#pragma unroll
            for (int j = 0; j < 4; j++)
                acc[i][j] = __builtin_amdgcn_mfma_f32_16x16x32_bf16(B[j], acur[i], acc[i][j], 0, 0, 0);
#pragma unroll
        for (int i = 0; i < 2; i++) {
#pragma unroll
            for (int jj = 0; jj < 4; jj++) {
                ushort4 s;
                s.x = f2b(acc[i][jj][0]); s.y = f2b(acc[i][jj][1]);
                s.z = f2b(acc[i][jj][2]); s.w = f2b(acc[i][jj][3]);
                *(ushort4*)(tw + m_ * 136 + jj * 16 + q * 4) = s;
            }
            __asm__ volatile("s_waitcnt lgkmcnt(0)" ::: "memory");
#pragma unroll
            for (int ri = 0; ri < 2; ri++) {
                int row = (lane >> 3) + ri * 8;
                int c = lane & 7;
                uint4 v = *(const uint4*)(tw + row * 136 + c * 8);
                int grow = m0 + i * 16 + row;
                if (grow < N_NODES)
                    *(uint4*)(z + (size_t)grow * 512 + bn * 64 + c * 8) = v;
            }
            __asm__ volatile("s_waitcnt lgkmcnt(0)" ::: "memory");
        }
    }
}

// edge2csr: one wave per node, single pass.  16 edges/instr, float4 store.
__global__ __launch_bounds__(256) void edge2csr(const unsigned int* __restrict__ packed,
                                                const int* __restrict__ rowptr,
                                                const unsigned short* __restrict__ z,
                                                const float* __restrict__ bias2,
                                                float* __restrict__ out) {
    __shared__ unsigned int ebuf[4 * 64];
    __shared__ float vbuf[4 * 64];
    int wave = threadIdx.x >> 6, lane = threadIdx.x & 63;
    int f = blockIdx.x * 4 + wave;
    if (f >= N_NODES) return;
    int s = rowptr[f], k = rowptr[f + 1] - s;
    int sub = lane & 3, p = lane >> 2;
    f32x4 acc = {0.f, 0.f, 0.f, 0.f};
    for (int base = 0; base < k; base += 64) {
        int e = base + lane;
        if (e < k) {
            unsigned int pk = packed[s + e];
            ebuf[wave * 64 + lane] = pk;
            vbuf[wave * 64 + lane] = 1.0f / (float)(pk >> 22);
        }
        int cnum = min(64, k - base);
        int nst = (cnum + 15) >> 4;
#pragma unroll 4
        for (int i = 0; i < nst; i++) {
            int ei = (i << 4) + p;
            if (ei < cnum) {
                unsigned int pk = ebuf[wave * 64 + ei];
                float v = vbuf[wave * 64 + ei];
                int t_ = pk & 0x1FFFF, r = (pk >> 17) & 31;
                ushort4 raw = *(const ushort4*)(z + (size_t)t_ * 512 + (r << 4) + (sub << 2));
                acc.x += v * b2f(raw.x); acc.y += v * b2f(raw.y);
                acc.z += v * b2f(raw.z); acc.w += v * b2f(raw.w);
            }
        }
    }
#pragma unroll
    for (int ofs = 4; ofs < 64; ofs <<= 1) {
        acc.x += __shfl_xor(acc.x, ofs, 64);
        acc.y += __shfl_xor(acc.y, ofs, 64);
        acc.z += __shfl_xor(acc.z, ofs, 64);
        acc.w += __shfl_xor(acc.w, ofs, 64);
    }
    if (p == 0) {
        int c = sub << 2;
        float4 o;
        o.x = acc.x + bias2[c + 0];
        o.y = acc.y + bias2[c + 1];
        o.z = acc.z + bias2[c + 2];
        o.w = acc.w + bias2[c + 3];
        *(float4*)(out + (size_t)f * 16 + c) = o;
    }
}

extern "C" void kernel_launch(void* const* d_in, const int* in_sizes, int n_in,
                              void* d_out, int out_size, void* d_ws, size_t ws_size,
                              hipStream_t stream) {
    (void)in_sizes; (void)n_in; (void)out_size; (void)ws_size;
    const float* emb    = (const float*)d_in[0];
    const float* comps1 = (const float*)d_in[1];
    const float* bases1 = (const float*)d_in[2];
    const float* comps2 = (const float*)d_in[3];
    const float* bases2 = (const float*)d_in[4];
    const float* bias1  = (const float*)d_in[5];
    const float* bias2  = (const float*)d_in[6];
    const int* rel = (const int*)d_in[7];
    const int* fr  = (const int*)d_in[8];
    const int* to  = (const int*)d_in[9];
    float* out = (float*)d_out;
    char* ws = (char*)d_ws;

    // workspace layout (bytes); embb region now unused (kemb deleted)
    int* gCursor         = (int*)(ws);                        // 1,568
    int* bucketBase      = (int*)(ws + 2048);                 // 1,568
    int* rowptr          = (int*)(ws + 4096);                 // 401,412
    unsigned int* packed = (unsigned int*)(ws + 406528);      // 12,800,000
    unsigned short* h1b  = (unsigned short*)(ws + 13206528);  // 6,406,144 (N_PAD x 32)
    unsigned short* w1T  = (unsigned short*)(ws + 19612672);  // 262,144
    unsigned short* w2T  = (unsigned short*)(ws + 19874816);  // 32,768
    unsigned short* xw   = (unsigned short*)(ws + 45532160);  // 204,800,000
    unsigned short* z    = xw;                 // alias: xw dead before gemm2
    unsigned int* stage  = (unsigned int*)xw;  // alias: stage dead before gemm1

    kcur<<<2, 256, 0, stream>>>(gCursor);
    kw1<<<512, 256, 0, stream>>>(comps1, bases1, w1T);
    kw2<<<64, 256, 0, stream>>>(comps2, bases2, w2T);
    kbinA<<<(E_EDGES + EPB - 1) / EPB, 256, 0, stream>>>(rel, fr, to, gCursor, stage);
    kscan<<<1, 512, 0, stream>>>(gCursor, bucketBase);
    kscatter2<<<NB, 256, 0, stream>>>(stage, gCursor, bucketBase, rowptr, packed);
    gemm1<<<1568, 256, 0, stream>>>(emb, w1T, xw);     // 8 xcd * 4 bn4 * 49 mgh
    edge1csr<<<25000, 256, 0, stream>>>(packed, rowptr, xw, bias1, h1b);
    gemm2<<<832, 256, 0, stream>>>(h1b, w2T, z);       // 8 xcd * 8 bn * 13 mgl
    edge2csr<<<25000, 256, 0, stream>>>(packed, rowptr, z, bias2, out);
}

// Round 10
// 433.606 us; speedup vs baseline: 1.3938x; 1.0851x over previous
//
#include <hip/hip_runtime.h>

// RGCN embedding, MI355X.  R19: revert R18's inline-f32 gemm1 (falsified:
// 78->138us — cvt2 asm at the prefetch point forces vmcnt(0) immediately,
// killing the ping-pong pipeline; prefetched data must stay untouched until
// consume).  Back to R14: kemb + bf16 gemm1 + wide-store XCD-local epilogue.
// Kept from R18: kbinA EPB=4096 (sortbuf 16KB, LDS ~25KB -> ~2x resident
// blocks; R17 measured kbinA 46us @ 12.8% occupancy with 42KB LDS).
#define N_NODES 100000
#define N_PAD   100096
#define E_EDGES 3200000
#define NB      392            // buckets of 256 nodes
#define BCAP    12288
#define EPB     4096           // edges per kbinA block (16/thread)

typedef float f32x4 __attribute__((ext_vector_type(4)));
typedef __bf16 bf16x8 __attribute__((ext_vector_type(8)));

__device__ __forceinline__ float b2f(unsigned int u) {
    union { unsigned int i; float f; } x; x.i = u << 16; return x.f;
}
__device__ __forceinline__ unsigned short f2b(float f) {
    union { float f; unsigned int i; } x; x.f = f;
    unsigned int u = x.i + 0x7FFFu + ((x.i >> 16) & 1u);
    return (unsigned short)(u >> 16);
}
// pack 2 f32 -> 2 bf16 (RNE), lo in bits[15:0]
__device__ __forceinline__ unsigned int cvt2(float lo, float hi) {
    unsigned int r;
    asm("v_cvt_pk_bf16_f32 %0, %1, %2" : "=v"(r) : "v"(lo), "v"(hi));
    return r;
}

__global__ __launch_bounds__(256) void kcur(int* __restrict__ gCursor) {
    int id = blockIdx.x * 256 + threadIdx.x;
    if (id < NB) gCursor[id] = id * BCAP;
}

// emb f32 -> bf16, padded to N_PAD rows (pad = 0)
__global__ __launch_bounds__(256) void kemb(const float* __restrict__ emb,
                                            unsigned short* __restrict__ embb) {
    int id = blockIdx.x * 256 + threadIdx.x;
    if (id >= N_PAD * 128 / 8) return;
    size_t base = (size_t)id * 8;
    ushort4 o0 = {0, 0, 0, 0}, o1 = {0, 0, 0, 0};
    if (base < (size_t)N_NODES * 128) {
        float4 v0 = *(const float4*)(emb + base);
        float4 v1 = *(const float4*)(emb + base + 4);
        o0.x = f2b(v0.x); o0.y = f2b(v0.y); o0.z = f2b(v0.z); o0.w = f2b(v0.w);
        o1.x = f2b(v1.x); o1.y = f2b(v1.y); o1.z = f2b(v1.z); o1.w = f2b(v1.w);
    }
    *(ushort4*)(embb + base) = o0;
    *(ushort4*)(embb + base + 4) = o1;
}

// w1T[j][k] = sum_b comps1[r,b]*bases1[b,k,h], j=r*32+h  (bf16, [1024][128])
__global__ __launch_bounds__(256) void kw1(const float* __restrict__ comps1,
                                           const float* __restrict__ bases1,
                                           unsigned short* __restrict__ w1T) {
    int id = blockIdx.x * 256 + threadIdx.x;
    if (id >= 1024 * 128) return;
    int k = id & 127, j = id >> 7;
    int r = j >> 5, h = j & 31;
    float s = 0.f;
#pragma unroll
    for (int b = 0; b < 16; b++)
        s += comps1[r * 16 + b] * bases1[b * 4096 + k * 32 + h];
    w1T[(size_t)j * 128 + k] = f2b(s);
}

// w2T[j2][h] = sum_b comps2[r,b]*bases2[b,h,c], j2=r*16+c  (bf16, [512][32])
__global__ __launch_bounds__(256) void kw2(const float* __restrict__ comps2,
                                           const float* __restrict__ bases2,
                                           unsigned short* __restrict__ w2T) {
    int id = blockIdx.x * 256 + threadIdx.x;
    if (id >= 512 * 32) return;
    int h = id & 31, j = id >> 5;
    int r = j >> 4, c = j & 15;
    float s = 0.f;
#pragma unroll
    for (int b = 0; b < 16; b++)
        s += comps2[r * 16 + b] * bases2[b * 512 + h * 16 + c];
    w2T[(size_t)j * 32 + h] = f2b(s);
}

// Single-pass in-block counting sort by bucket (fr>>8).  EPB=4096 (16/thread):
// sortbuf 16KB -> ~2x resident blocks vs EPB=8192.
__global__ __launch_bounds__(256) void kbinA(const int* __restrict__ rel,
                                             const int* __restrict__ fr,
                                             const int* __restrict__ to,
                                             int* __restrict__ gCursor,
                                             unsigned int* __restrict__ stage) {
    __shared__ int cnt[NB];
    __shared__ int lexcl[NB + 1];
    __shared__ int sdelta[NB];
    __shared__ int sa[512], sb_[512];
    __shared__ unsigned int sortbuf[EPB];
    int tid = threadIdx.x;
    int g40 = blockIdx.x * (EPB / 4);          // int4-group base
    unsigned int w_[16];
    int bk[16];
    for (int i = tid; i < NB; i += 256) cnt[i] = 0;
    __syncthreads();
    // load 16 edges into registers, LDS histogram
#pragma unroll
    for (int i = 0; i < EPB / 1024; i++) {
        int g4 = g40 + i * 256 + tid;
        if (g4 < E_EDGES / 4) {
            int4 f4 = ((const int4*)fr)[g4];
            int4 r4 = ((const int4*)rel)[g4];
            int4 t4 = ((const int4*)to)[g4];
            int fa[4] = {f4.x, f4.y, f4.z, f4.w};
            int ra[4] = {r4.x, r4.y, r4.z, r4.w};
            int ta[4] = {t4.x, t4.y, t4.z, t4.w};
#pragma unroll
            for (int u = 0; u < 4; u++) {
                int b = fa[u] >> 8;
                w_[i * 4 + u] = ((unsigned int)(fa[u] & 255) << 22) |
                                ((unsigned int)ra[u] << 17) | (unsigned int)ta[u];
                bk[i * 4 + u] = b;
                atomicAdd(&cnt[b], 1);
            }
        } else {
#pragma unroll
            for (int u = 0; u < 4; u++) bk[i * 4 + u] = -1;
        }
    }
    __syncthreads();
    // inclusive scan of cnt[0..NB) over padded 512 domain (256 thr x 2 elem)
    sa[tid] = (tid < NB) ? cnt[tid] : 0;
    sa[tid + 256] = (tid + 256 < NB) ? cnt[tid + 256] : 0;
    __syncthreads();
    int* src = sa; int* dst = sb_;
    for (int ofs = 1; ofs < 512; ofs <<= 1) {
        int x0 = src[tid];
        if (tid >= ofs) x0 += src[tid - ofs];
        int x1 = src[tid + 256] + src[tid + 256 - ofs];
        __syncthreads();
        dst[tid] = x0; dst[tid + 256] = x1;
        __syncthreads();
        int* tmp = src; src = dst; dst = tmp;
    }
    // reserve global ranges, build local offsets
    for (int b = tid; b < NB; b += 256) {
        int c = cnt[b];
        int lex = src[b] - c;
        lexcl[b] = lex;
        int gb = 0;
        if (c) gb = atomicAdd(&gCursor[b], c);
        sdelta[b] = gb - lex;
        cnt[b] = 0;                       // reuse as rank counter
    }
    if (tid == 0) lexcl[NB] = src[NB - 1];
    __syncthreads();
    // rank-scatter into LDS sorted buffer
#pragma unroll
    for (int i = 0; i < 16; i++) {
        if (bk[i] >= 0) {
            int rank = atomicAdd(&cnt[bk[i]], 1);
            sortbuf[lexcl[bk[i]] + rank] = w_[i];
        }
    }
    __syncthreads();
    // flush per-bucket contiguous runs
    int wv = tid >> 6, lane = tid & 63;
    for (int b = wv; b < NB; b += 4) {
        int s = lexcl[b], e = lexcl[b + 1];
        int d = sdelta[b];
        for (int i = s + lane; i < e; i += 64)
            stage[d + i] = sortbuf[i];
    }
}

// exclusive scan of bucket counts -> bucketBase
__global__ __launch_bounds__(512) void kscan(const int* __restrict__ gCursor,
                                             int* __restrict__ bucketBase) {
    __shared__ int a[512], b[512];
    int t = threadIdx.x;
    int v = (t < NB) ? (gCursor[t] - t * BCAP) : 0;
    a[t] = v;
    __syncthreads();
    int* src = a; int* dst = b;
    for (int ofs = 1; ofs < 512; ofs <<= 1) {
        int x = src[t];
        if (t >= ofs) x += src[t - ofs];
        __syncthreads();
        dst[t] = x;
        __syncthreads();
        int* tmp = src; src = dst; dst = tmp;
    }
    if (t < NB) bucketBase[t] = src[t] - v;
}

// Per-bucket: LDS node-hist -> scan -> rowptr; (node,rel)-hist -> deg;
// scatter packed = (deg<<22)|(rel<<17)|to.  uint4 stage loads.
__global__ __launch_bounds__(256) void kscatter2(const unsigned int* __restrict__ stage,
                                                 const int* __restrict__ gCursor,
                                                 const int* __restrict__ bucketBase,
                                                 int* __restrict__ rowptr,
                                                 unsigned int* __restrict__ packed) {
    __shared__ int hist[256], hexcl[256], rk[256], sa[256], sb[256];
    __shared__ int hist2[256 * 32];
    int b = blockIdx.x, t = threadIdx.x;
    int nb = gCursor[b] - b * BCAP;
    int sbase = b * BCAP;
    int gbase = bucketBase[b];
    int nb4 = nb >> 2;
    hist[t] = 0; rk[t] = 0;
    for (int i = t; i < 256 * 32; i += 256) hist2[i] = 0;
    __syncthreads();
    for (int i4 = t; i4 < nb4; i4 += 256) {
        uint4 p4 = ((const uint4*)(stage + sbase))[i4];
        unsigned int pa[4] = {p4.x, p4.y, p4.z, p4.w};
#pragma unroll
        for (int u = 0; u < 4; u++) {
            atomicAdd(&hist[pa[u] >> 22], 1);
            atomicAdd(&hist2[((pa[u] >> 22) << 5) | ((pa[u] >> 17) & 31)], 1);
        }
    }
    for (int i = (nb4 << 2) + t; i < nb; i += 256) {
        unsigned int pk = stage[sbase + i];
        atomicAdd(&hist[pk >> 22], 1);
        atomicAdd(&hist2[((pk >> 22) << 5) | ((pk >> 17) & 31)], 1);
    }
    __syncthreads();
    int v = hist[t];
    sa[t] = v;
    __syncthreads();
    int* src = sa; int* dst = sb;
    for (int ofs = 1; ofs < 256; ofs <<= 1) {
        int x = src[t];
        if (t >= ofs) x += src[t - ofs];
        __syncthreads();
        dst[t] = x;
        __syncthreads();
        int* tmp = src; src = dst; dst = tmp;
    }
    int excl = src[t] - v;
    hexcl[t] = excl;
    rowptr[b * 256 + t] = gbase + excl;
    __syncthreads();
    for (int i4 = t; i4 < nb4; i4 += 256) {
        uint4 p4 = ((const uint4*)(stage + sbase))[i4];
        unsigned int pa[4] = {p4.x, p4.y, p4.z, p4.w};
#pragma unroll
        for (int u = 0; u < 4; u++) {
            int frlo = pa[u] >> 22;
            int rank = atomicAdd(&rk[frlo], 1);
            int dg = min(hist2[(frlo << 5) | ((pa[u] >> 17) & 31)], 1023);
            packed[gbase + hexcl[frlo] + rank] = ((unsigned int)dg << 22) | (pa[u] & 0x3FFFFFu);
        }
    }
    for (int i = (nb4 << 2) + t; i < nb; i += 256) {
        unsigned int pk = stage[sbase + i];
        int frlo = pk >> 22;
        int rank = atomicAdd(&rk[frlo], 1);
        int dg = min(hist2[(frlo << 5) | ((pk >> 17) & 31)], 1023);
        packed[gbase + hexcl[frlo] + rank] = ((unsigned int)dg << 22) | (pk & 0x3FFFFFu);
    }
}

// GEMM1 (row-shared block + merged wide epilogue, XCD-local): 4 waves share the
// same 16 rows, each owns 64 cols.  mg = mgh*8+xcd so all 4 bn4-blocks of one
// 256-row A-slab run on ONE XCD (slab read once into its L2).  Ping-pong LDS
// tile -> 1 barrier/iter.  Stores: 512B contiguous per row.
__global__ __launch_bounds__(256) void gemm1(const unsigned short* __restrict__ embb,
                                             const unsigned short* __restrict__ w1T,
                                             unsigned short* __restrict__ xw) {
    __shared__ unsigned short tile[2][16 * 260];
    int id = blockIdx.x;
    int xcd = id & 7;
    int k_ = id >> 3;
    int bn4 = k_ & 3, mgh = k_ >> 2;           // mgh in [0,49)
    int mg = mgh * 8 + xcd;                    // [0,392)
    int mrow0 = mg * 256;
    if (mrow0 >= N_PAD) return;                // mg=391 empty
    int lane = threadIdx.x & 63, wave = threadIdx.x >> 6;
    int bn = bn4 * 4 + wave;
    int m_ = lane & 15, q = lane >> 4;
    bf16x8 B[4][4];
    const unsigned short* Bbase = w1T + (size_t)(bn * 64 + m_) * 128 + q * 8;
#pragma unroll
    for (int j = 0; j < 4; j++)
#pragma unroll
        for (int k0 = 0; k0 < 4; k0++)
            B[j][k0] = *(const bf16x8*)(Bbase + j * 16 * 128 + k0 * 32);
    const unsigned short* Abase = embb + (size_t)(mrow0 + m_) * 128 + q * 8;
    bf16x8 a0[4], a1[4];
#pragma unroll
    for (int k0 = 0; k0 < 4; k0++)
        a0[k0] = *(const bf16x8*)(Abase + k0 * 32);
#pragma unroll
    for (int t = 0; t < 16; t++) {
        int m0 = mrow0 + t * 16;
        unsigned short* tw = tile[t & 1];
        bf16x8* acur = (t & 1) ? a1 : a0;
        bf16x8* anext = (t & 1) ? a0 : a1;
        if (t < 15) {
#pragma unroll
            for (int k0 = 0; k0 < 4; k0++)
                anext[k0] = *(const bf16x8*)(Abase + (size_t)(t + 1) * 16 * 128 + k0 * 32);
        }
        f32x4 acc[4] = {};
#pragma unroll
        for (int k0 = 0; k0 < 4; k0++)
#pragma unroll
            for (int j = 0; j < 4; j++)
                acc[j] = __builtin_amdgcn_mfma_f32_16x16x32_bf16(B[j][k0], acur[k0], acc[j], 0, 0, 0);
        // pack: row m_, cols wave*64 + jj*16 + q*4 (+reg)
#pragma unroll
        for (int jj = 0; jj < 4; jj++) {
            uint2 s;
            s.x = cvt2(acc[jj][0], acc[jj][1]);
            s.y = cvt2(acc[jj][2], acc[jj][3]);
            *(uint2*)(tw + m_ * 260 + wave * 64 + jj * 16 + q * 4) = s;
        }
        __syncthreads();
        // merged store: 512 uint4 chunks (16 rows x 512B), 2 per thread
#pragma unroll
        for (int half = 0; half < 2; half++) {
            int idx = threadIdx.x + half * 256;
            int row = idx >> 5, c16 = idx & 31;
            uint4 v = *(const uint4*)(tw + row * 260 + c16 * 8);
            int grow = m0 + row;
            if (grow < N_NODES)
                *(uint4*)(xw + (size_t)grow * 1024 + bn4 * 256 + c16 * 8) = v;
        }
    }
}

// edge1csr: one wave per node, single pass (deg packed).  8 edges/instr.
__global__ __launch_bounds__(256) void edge1csr(const unsigned int* __restrict__ packed,
                                                const int* __restrict__ rowptr,
                                                const unsigned short* __restrict__ xw,
                                                const float* __restrict__ bias1,
                                                unsigned short* __restrict__ h1b) {
    __shared__ unsigned int ebuf[4 * 64];
    __shared__ float vbuf[4 * 64];
    int wave = threadIdx.x >> 6, lane = threadIdx.x & 63;
    int f = blockIdx.x * 4 + wave;
    if (f >= N_NODES) return;
    int s = rowptr[f], k = rowptr[f + 1] - s;
    int sub = lane & 7, p = lane >> 3;
    f32x4 acc = {0.f, 0.f, 0.f, 0.f};
    for (int base = 0; base < k; base += 64) {
        int e = base + lane;
        if (e < k) {
            unsigned int pk = packed[s + e];
            ebuf[wave * 64 + lane] = pk;
            vbuf[wave * 64 + lane] = 1.0f / (float)(pk >> 22);
        }
        int cnum = min(64, k - base);
        int nst = (cnum + 7) >> 3;
#pragma unroll 4
        for (int i = 0; i < nst; i++) {
            int ei = (i << 3) + p;
            if (ei < cnum) {
                unsigned int pk = ebuf[wave * 64 + ei];
                float v = vbuf[wave * 64 + ei];
                int t_ = pk & 0x1FFFF, r = (pk >> 17) & 31;
                ushort4 raw = *(const ushort4*)(xw + (size_t)t_ * 1024 + (r << 5) + (sub << 2));
                acc.x += v * b2f(raw.x); acc.y += v * b2f(raw.y);
                acc.z += v * b2f(raw.z); acc.w += v * b2f(raw.w);
            }
        }
    }
#pragma unroll
    for (int ofs = 8; ofs < 64; ofs <<= 1) {
        acc.x += __shfl_xor(acc.x, ofs, 64);
        acc.y += __shfl_xor(acc.y, ofs, 64);
        acc.z += __shfl_xor(acc.z, ofs, 64);
        acc.w += __shfl_xor(acc.w, ofs, 64);
    }
    if (p == 0) {
        int h = sub << 2;
        ushort4 o;
        o.x = f2b(fmaxf(acc.x + bias1[h + 0], 0.f));
        o.y = f2b(fmaxf(acc.y + bias1[h + 1], 0.f));
        o.z = f2b(fmaxf(acc.z + bias1[h + 2], 0.f));
        o.w = f2b(fmaxf(acc.w + bias1[h + 3], 0.f));
        *(ushort4*)(h1b + (size_t)f * 32 + h) = o;
    }
}

// GEMM2 (streaming-wave + LDS-pack epilogue, R11): z[m][j2] = sum_h h1b[m][h]*w2T[j2][h].
__global__ __launch_bounds__(256) void gemm2(const unsigned short* __restrict__ h1b,
                                             const unsigned short* __restrict__ w2T,
                                             unsigned short* __restrict__ z) {
    __shared__ unsigned short ldsT[4 * 16 * 136];
    int id = blockIdx.x;
    int xcd = id & 7, w = id >> 3;
    int bn = w & 7, mgl = w >> 3;
    int mg = mgl * 8 + xcd;
    if (mg >= 98) return;
    int lane = threadIdx.x & 63, wave = threadIdx.x >> 6;
    int m_ = lane & 15, q = lane >> 4;
    unsigned short* tw = &ldsT[wave * 16 * 136];
    bf16x8 B[4];
    const unsigned short* Bbase = w2T + (size_t)(bn * 64 + m_) * 32 + q * 8;
#pragma unroll
    for (int j = 0; j < 4; j++)
        B[j] = *(const bf16x8*)(Bbase + j * 16 * 32);
    int mrow0 = mg * 1024 + wave * 32;
    const unsigned short* Abase = h1b + (size_t)(mrow0 + m_) * 32 + q * 8;
    bf16x8 a0[2], a1[2];
    if (mrow0 < N_PAD) {
        a0[0] = *(const bf16x8*)(Abase);
        a0[1] = *(const bf16x8*)(Abase + 16 * 32);
    }
#pragma unroll
    for (int t = 0; t < 8; t++) {
        int m0 = mrow0 + t * 128;
        if (m0 >= N_PAD) break;
        bf16x8* acur = (t & 1) ? a1 : a0;
        bf16x8* anext = (t & 1) ? a0 : a1;
        if (t < 7 && m0 + 128 < N_PAD) {
            anext[0] = *(const bf16x8*)(Abase + (size_t)(t + 1) * 128 * 32);
            anext[1] = *(const bf16x8*)(Abase + (size_t)(t + 1) * 128 * 32 + 16 * 32);
        }
        f32x4 acc[2][4] = {};
#pragma unroll
        for (int i = 0; i < 2; i++)
#pragma unroll
            for (int j = 0; j < 4; j++)
                acc[i][j] = __builtin_amdgcn_mfma_f32_16x16x32_bf16(B[j], acur[i], acc[i][j], 0, 0, 0);
#pragma unroll
        for (int i = 0; i < 2; i++) {
#pragma unroll
            for (int jj = 0; jj < 4; jj++) {
                ushort4 s;
                s.x = f2b(acc[i][jj][0]); s.y = f2b(acc[i][jj][1]);
                s.z = f2b(acc[i][jj][2]); s.w = f2b(acc[i][jj][3]);
                *(ushort4*)(tw + m_ * 136 + jj * 16 + q * 4) = s;
            }
            __asm__ volatile("s_waitcnt lgkmcnt(0)" ::: "memory");
#pragma unroll
            for (int ri = 0; ri < 2; ri++) {
                int row = (lane >> 3) + ri * 8;
                int c = lane & 7;
                uint4 v = *(const uint4*)(tw + row * 136 + c * 8);
                int grow = m0 + i * 16 + row;
                if (grow < N_NODES)
                    *(uint4*)(z + (size_t)grow * 512 + bn * 64 + c * 8) = v;
            }
            __asm__ volatile("s_waitcnt lgkmcnt(0)" ::: "memory");
        }
    }
}

// edge2csr: one wave per node, single pass.  16 edges/instr, float4 store.
__global__ __launch_bounds__(256) void edge2csr(const unsigned int* __restrict__ packed,
                                                const int* __restrict__ rowptr,
                                                const unsigned short* __restrict__ z,
                                                const float* __restrict__ bias2,
                                                float* __restrict__ out) {
    __shared__ unsigned int ebuf[4 * 64];
    __shared__ float vbuf[4 * 64];
    int wave = threadIdx.x >> 6, lane = threadIdx.x & 63;
    int f = blockIdx.x * 4 + wave;
    if (f >= N_NODES) return;
    int s = rowptr[f], k = rowptr[f + 1] - s;
    int sub = lane & 3, p = lane >> 2;
    f32x4 acc = {0.f, 0.f, 0.f, 0.f};
    for (int base = 0; base < k; base += 64) {
        int e = base + lane;
        if (e < k) {
            unsigned int pk = packed[s + e];
            ebuf[wave * 64 + lane] = pk;
            vbuf[wave * 64 + lane] = 1.0f / (float)(pk >> 22);
        }
        int cnum = min(64, k - base);
        int nst = (cnum + 15) >> 4;
#pragma unroll 4
        for (int i = 0; i < nst; i++) {
            int ei = (i << 4) + p;
            if (ei < cnum) {
                unsigned int pk = ebuf[wave * 64 + ei];
                float v = vbuf[wave * 64 + ei];
                int t_ = pk & 0x1FFFF, r = (pk >> 17) & 31;
                ushort4 raw = *(const ushort4*)(z + (size_t)t_ * 512 + (r << 4) + (sub << 2));
                acc.x += v * b2f(raw.x); acc.y += v * b2f(raw.y);
                acc.z += v * b2f(raw.z); acc.w += v * b2f(raw.w);
            }
        }
    }
#pragma unroll
    for (int ofs = 4; ofs < 64; ofs <<= 1) {
        acc.x += __shfl_xor(acc.x, ofs, 64);
        acc.y += __shfl_xor(acc.y, ofs, 64);
        acc.z += __shfl_xor(acc.z, ofs, 64);
        acc.w += __shfl_xor(acc.w, ofs, 64);
    }
    if (p == 0) {
        int c = sub << 2;
        float4 o;
        o.x = acc.x + bias2[c + 0];
        o.y = acc.y + bias2[c + 1];
        o.z = acc.z + bias2[c + 2];
        o.w = acc.w + bias2[c + 3];
        *(float4*)(out + (size_t)f * 16 + c) = o;
    }
}

extern "C" void kernel_launch(void* const* d_in, const int* in_sizes, int n_in,
                              void* d_out, int out_size, void* d_ws, size_t ws_size,
                              hipStream_t stream) {
    (void)in_sizes; (void)n_in; (void)out_size; (void)ws_size;
    const float* emb    = (const float*)d_in[0];
    const float* comps1 = (const float*)d_in[1];
    const float* bases1 = (const float*)d_in[2];
    const float* comps2 = (const float*)d_in[3];
    const float* bases2 = (const float*)d_in[4];
    const float* bias1  = (const float*)d_in[5];
    const float* bias2  = (const float*)d_in[6];
    const int* rel = (const int*)d_in[7];
    const int* fr  = (const int*)d_in[8];
    const int* to  = (const int*)d_in[9];
    float* out = (float*)d_out;
    char* ws = (char*)d_ws;

    // workspace layout (bytes); total ~250.3 MB
    int* gCursor         = (int*)(ws);                        // 1,568
    int* bucketBase      = (int*)(ws + 2048);                 // 1,568
    int* rowptr          = (int*)(ws + 4096);                 // 401,412
    unsigned int* packed = (unsigned int*)(ws + 406528);      // 12,800,000
    unsigned short* h1b  = (unsigned short*)(ws + 13206528);  // 6,406,144 (N_PAD x 32)
    unsigned short* w1T  = (unsigned short*)(ws + 19612672);  // 262,144
    unsigned short* w2T  = (unsigned short*)(ws + 19874816);  // 32,768
    unsigned short* embb = (unsigned short*)(ws + 19907584);  // 25,624,576 (N_PAD x 128)
    unsigned short* xw   = (unsigned short*)(ws + 45532160);  // 204,800,000
    unsigned short* z    = xw;                 // alias: xw dead before gemm2
    unsigned int* stage  = (unsigned int*)xw;  // alias: stage dead before gemm1

    kcur<<<2, 256, 0, stream>>>(gCursor);
    kemb<<<6256, 256, 0, stream>>>(emb, embb);
    kw1<<<512, 256, 0, stream>>>(comps1, bases1, w1T);
    kw2<<<64, 256, 0, stream>>>(comps2, bases2, w2T);
    kbinA<<<(E_EDGES + EPB - 1) / EPB, 256, 0, stream>>>(rel, fr, to, gCursor, stage);
    kscan<<<1, 512, 0, stream>>>(gCursor, bucketBase);
    kscatter2<<<NB, 256, 0, stream>>>(stage, gCursor, bucketBase, rowptr, packed);
    gemm1<<<1568, 256, 0, stream>>>(embb, w1T, xw);    // 8 xcd * 4 bn4 * 49 mgh
    edge1csr<<<25000, 256, 0, stream>>>(packed, rowptr, xw, bias1, h1b);
    gemm2<<<832, 256, 0, stream>>>(h1b, w2T, z);       // 8 xcd * 8 bn * 13 mgl
    edge2csr<<<25000, 256, 0, stream>>>(packed, rowptr, z, bias2, out);
}

// Round 11
// 412.873 us; speedup vs baseline: 1.4638x; 1.0502x over previous
//
#include <hip/hip_runtime.h>

// RGCN embedding, MI355X.  R20: merge the independent front-end kernels
// (kbinA + kemb + kw1 + kw2) into one block-range-dispatched kernel `kfront`.
// Dependency audit: disjoint outputs (stage+gCursor / embb / w1T / w2T), no
// cross-reads -> safe to co-schedule.  kbinA blocks first (latency-bound,
// ~28us) so kemb/kw streaming blocks fill idle BW alongside instead of
// serializing (~59us front + 3 launch gaps -> ~40us).  All other kernels
// identical to R19 (= R14 + kbinA EPB 4096).
#define N_NODES 100000
#define N_PAD   100096
#define E_EDGES 3200000
#define NB      392            // buckets of 256 nodes
#define BCAP    12288
#define EPB     4096           // edges per kbinA block (16/thread)
#define NBIN    ((E_EDGES + EPB - 1) / EPB)    // 782 kbinA blocks
#define NEMB    6256                            // kemb blocks
#define NW1     512
#define NW2     64

typedef float f32x4 __attribute__((ext_vector_type(4)));
typedef __bf16 bf16x8 __attribute__((ext_vector_type(8)));

__device__ __forceinline__ float b2f(unsigned int u) {
    union { unsigned int i; float f; } x; x.i = u << 16; return x.f;
}
__device__ __forceinline__ unsigned short f2b(float f) {
    union { float f; unsigned int i; } x; x.f = f;
    unsigned int u = x.i + 0x7FFFu + ((x.i >> 16) & 1u);
    return (unsigned short)(u >> 16);
}
// pack 2 f32 -> 2 bf16 (RNE), lo in bits[15:0]
__device__ __forceinline__ unsigned int cvt2(float lo, float hi) {
    unsigned int r;
    asm("v_cvt_pk_bf16_f32 %0, %1, %2" : "=v"(r) : "v"(lo), "v"(hi));
    return r;
}

__global__ __launch_bounds__(256) void kcur(int* __restrict__ gCursor) {
    int id = blockIdx.x * 256 + threadIdx.x;
    if (id < NB) gCursor[id] = id * BCAP;
}

// Merged front-end: blocks [0,NBIN) = kbinA; [NBIN,NBIN+NEMB) = kemb;
// then kw1, kw2.  Independent outputs; kbinA first in dispatch order.
__global__ __launch_bounds__(256) void kfront(const int* __restrict__ rel,
                                              const int* __restrict__ fr,
                                              const int* __restrict__ to,
                                              int* __restrict__ gCursor,
                                              unsigned int* __restrict__ stage,
                                              const float* __restrict__ emb,
                                              unsigned short* __restrict__ embb,
                                              const float* __restrict__ comps1,
                                              const float* __restrict__ bases1,
                                              unsigned short* __restrict__ w1T,
                                              const float* __restrict__ comps2,
                                              const float* __restrict__ bases2,
                                              unsigned short* __restrict__ w2T) {
    int blk = blockIdx.x;
    int tid = threadIdx.x;
    if (blk < NBIN) {
        // ---- kbinA: single-pass in-block counting sort by bucket (fr>>8) ----
        __shared__ int cnt[NB];
        __shared__ int lexcl[NB + 1];
        __shared__ int sdelta[NB];
        __shared__ int sa[512], sb_[512];
        __shared__ unsigned int sortbuf[EPB];
        int g40 = blk * (EPB / 4);             // int4-group base
        unsigned int w_[16];
        int bk[16];
        for (int i = tid; i < NB; i += 256) cnt[i] = 0;
        __syncthreads();
#pragma unroll
        for (int i = 0; i < EPB / 1024; i++) {
            int g4 = g40 + i * 256 + tid;
            if (g4 < E_EDGES / 4) {
                int4 f4 = ((const int4*)fr)[g4];
                int4 r4 = ((const int4*)rel)[g4];
                int4 t4 = ((const int4*)to)[g4];
                int fa[4] = {f4.x, f4.y, f4.z, f4.w};
                int ra[4] = {r4.x, r4.y, r4.z, r4.w};
                int ta[4] = {t4.x, t4.y, t4.z, t4.w};
#pragma unroll
                for (int u = 0; u < 4; u++) {
                    int b = fa[u] >> 8;
                    w_[i * 4 + u] = ((unsigned int)(fa[u] & 255) << 22) |
                                    ((unsigned int)ra[u] << 17) | (unsigned int)ta[u];
                    bk[i * 4 + u] = b;
                    atomicAdd(&cnt[b], 1);
                }
            } else {
#pragma unroll
                for (int u = 0; u < 4; u++) bk[i * 4 + u] = -1;
            }
        }
        __syncthreads();
        sa[tid] = (tid < NB) ? cnt[tid] : 0;
        sa[tid + 256] = (tid + 256 < NB) ? cnt[tid + 256] : 0;
        __syncthreads();
        int* src = sa; int* dst = sb_;
        for (int ofs = 1; ofs < 512; ofs <<= 1) {
            int x0 = src[tid];
            if (tid >= ofs) x0 += src[tid - ofs];
            int x1 = src[tid + 256] + src[tid + 256 - ofs];
            __syncthreads();
            dst[tid] = x0; dst[tid + 256] = x1;
            __syncthreads();
            int* tmp = src; src = dst; dst = tmp;
        }
        for (int b = tid; b < NB; b += 256) {
            int c = cnt[b];
            int lex = src[b] - c;
            lexcl[b] = lex;
            int gb = 0;
            if (c) gb = atomicAdd(&gCursor[b], c);
            sdelta[b] = gb - lex;
            cnt[b] = 0;                   // reuse as rank counter
        }
        if (tid == 0) lexcl[NB] = src[NB - 1];
        __syncthreads();
#pragma unroll
        for (int i = 0; i < 16; i++) {
            if (bk[i] >= 0) {
                int rank = atomicAdd(&cnt[bk[i]], 1);
                sortbuf[lexcl[bk[i]] + rank] = w_[i];
            }
        }
        __syncthreads();
        int wv = tid >> 6, lane = tid & 63;
        for (int b = wv; b < NB; b += 4) {
            int s = lexcl[b], e = lexcl[b + 1];
            int d = sdelta[b];
            for (int i = s + lane; i < e; i += 64)
                stage[d + i] = sortbuf[i];
        }
    } else if (blk < NBIN + NEMB) {
        // ---- kemb: emb f32 -> bf16, padded to N_PAD rows (pad = 0) ----
        int id = (blk - NBIN) * 256 + tid;
        if (id >= N_PAD * 128 / 8) return;
        size_t base = (size_t)id * 8;
        ushort4 o0 = {0, 0, 0, 0}, o1 = {0, 0, 0, 0};
        if (base < (size_t)N_NODES * 128) {
            float4 v0 = *(const float4*)(emb + base);
            float4 v1 = *(const float4*)(emb + base + 4);
            o0.x = f2b(v0.x); o0.y = f2b(v0.y); o0.z = f2b(v0.z); o0.w = f2b(v0.w);
            o1.x = f2b(v1.x); o1.y = f2b(v1.y); o1.z = f2b(v1.z); o1.w = f2b(v1.w);
        }
        *(ushort4*)(embb + base) = o0;
        *(ushort4*)(embb + base + 4) = o1;
    } else if (blk < NBIN + NEMB + NW1) {
        // ---- kw1: w1T[j][k] = sum_b comps1[r,b]*bases1[b,k,h], j=r*32+h ----
        int id = (blk - NBIN - NEMB) * 256 + tid;
        if (id >= 1024 * 128) return;
        int k = id & 127, j = id >> 7;
        int r = j >> 5, h = j & 31;
        float s = 0.f;
#pragma unroll
        for (int b = 0; b < 16; b++)
            s += comps1[r * 16 + b] * bases1[b * 4096 + k * 32 + h];
        w1T[(size_t)j * 128 + k] = f2b(s);
    } else {
        // ---- kw2: w2T[j2][h] = sum_b comps2[r,b]*bases2[b,h,c], j2=r*16+c ----
        int id = (blk - NBIN - NEMB - NW1) * 256 + tid;
        if (id >= 512 * 32) return;
        int h = id & 31, j = id >> 5;
        int r = j >> 4, c = j & 15;
        float s = 0.f;
#pragma unroll
        for (int b = 0; b < 16; b++)
            s += comps2[r * 16 + b] * bases2[b * 512 + h * 16 + c];
        w2T[(size_t)j * 32 + h] = f2b(s);
    }
}

// exclusive scan of bucket counts -> bucketBase
__global__ __launch_bounds__(512) void kscan(const int* __restrict__ gCursor,
                                             int* __restrict__ bucketBase) {
    __shared__ int a[512], b[512];
    int t = threadIdx.x;
    int v = (t < NB) ? (gCursor[t] - t * BCAP) : 0;
    a[t] = v;
    __syncthreads();
    int* src = a; int* dst = b;
    for (int ofs = 1; ofs < 512; ofs <<= 1) {
        int x = src[t];
        if (t >= ofs) x += src[t - ofs];
        __syncthreads();
        dst[t] = x;
        __syncthreads();
        int* tmp = src; src = dst; dst = tmp;
    }
    if (t < NB) bucketBase[t] = src[t] - v;
}

// Per-bucket: LDS node-hist -> scan -> rowptr; (node,rel)-hist -> deg;
// scatter packed = (deg<<22)|(rel<<17)|to.  uint4 stage loads.
__global__ __launch_bounds__(256) void kscatter2(const unsigned int* __restrict__ stage,
                                                 const int* __restrict__ gCursor,
                                                 const int* __restrict__ bucketBase,
                                                 int* __restrict__ rowptr,
                                                 unsigned int* __restrict__ packed) {
    __shared__ int hist[256], hexcl[256], rk[256], sa[256], sb[256];
    __shared__ int hist2[256 * 32];
    int b = blockIdx.x, t = threadIdx.x;
    int nb = gCursor[b] - b * BCAP;
    int sbase = b * BCAP;
    int gbase = bucketBase[b];
    int nb4 = nb >> 2;
    hist[t] = 0; rk[t] = 0;
    for (int i = t; i < 256 * 32; i += 256) hist2[i] = 0;
    __syncthreads();
    for (int i4 = t; i4 < nb4; i4 += 256) {
        uint4 p4 = ((const uint4*)(stage + sbase))[i4];
        unsigned int pa[4] = {p4.x, p4.y, p4.z, p4.w};
#pragma unroll
        for (int u = 0; u < 4; u++) {
            atomicAdd(&hist[pa[u] >> 22], 1);
            atomicAdd(&hist2[((pa[u] >> 22) << 5) | ((pa[u] >> 17) & 31)], 1);
        }
    }
    for (int i = (nb4 << 2) + t; i < nb; i += 256) {
        unsigned int pk = stage[sbase + i];
        atomicAdd(&hist[pk >> 22], 1);
        atomicAdd(&hist2[((pk >> 22) << 5) | ((pk >> 17) & 31)], 1);
    }
    __syncthreads();
    int v = hist[t];
    sa[t] = v;
    __syncthreads();
    int* src = sa; int* dst = sb;
    for (int ofs = 1; ofs < 256; ofs <<= 1) {
        int x = src[t];
        if (t >= ofs) x += src[t - ofs];
        __syncthreads();
        dst[t] = x;
        __syncthreads();
        int* tmp = src; src = dst; dst = tmp;
    }
    int excl = src[t] - v;
    hexcl[t] = excl;
    rowptr[b * 256 + t] = gbase + excl;
    __syncthreads();
    for (int i4 = t; i4 < nb4; i4 += 256) {
        uint4 p4 = ((const uint4*)(stage + sbase))[i4];
        unsigned int pa[4] = {p4.x, p4.y, p4.z, p4.w};
#pragma unroll
        for (int u = 0; u < 4; u++) {
            int frlo = pa[u] >> 22;
            int rank = atomicAdd(&rk[frlo], 1);
            int dg = min(hist2[(frlo << 5) | ((pa[u] >> 17) & 31)], 1023);
            packed[gbase + hexcl[frlo] + rank] = ((unsigned int)dg << 22) | (pa[u] & 0x3FFFFFu);
        }
    }
    for (int i = (nb4 << 2) + t; i < nb; i += 256) {
        unsigned int pk = stage[sbase + i];
        int frlo = pk >> 22;
        int rank = atomicAdd(&rk[frlo], 1);
        int dg = min(hist2[(frlo << 5) | ((pk >> 17) & 31)], 1023);
        packed[gbase + hexcl[frlo] + rank] = ((unsigned int)dg << 22) | (pk & 0x3FFFFFu);
    }
}

// GEMM1 (row-shared block + merged wide epilogue, XCD-local): 4 waves share the
// same 16 rows, each owns 64 cols.  mg = mgh*8+xcd so all 4 bn4-blocks of one
// 256-row A-slab run on ONE XCD (slab read once into its L2).  Ping-pong LDS
// tile -> 1 barrier/iter.  Stores: 512B contiguous per row.
__global__ __launch_bounds__(256) void gemm1(const unsigned short* __restrict__ embb,
                                             const unsigned short* __restrict__ w1T,
                                             unsigned short* __restrict__ xw) {
    __shared__ unsigned short tile[2][16 * 260];
    int id = blockIdx.x;
    int xcd = id & 7;
    int k_ = id >> 3;
    int bn4 = k_ & 3, mgh = k_ >> 2;           // mgh in [0,49)
    int mg = mgh * 8 + xcd;                    // [0,392)
    int mrow0 = mg * 256;
    if (mrow0 >= N_PAD) return;                // mg=391 empty
    int lane = threadIdx.x & 63, wave = threadIdx.x >> 6;
    int bn = bn4 * 4 + wave;
    int m_ = lane & 15, q = lane >> 4;
    bf16x8 B[4][4];
    const unsigned short* Bbase = w1T + (size_t)(bn * 64 + m_) * 128 + q * 8;
#pragma unroll
    for (int j = 0; j < 4; j++)
#pragma unroll
        for (int k0 = 0; k0 < 4; k0++)
            B[j][k0] = *(const bf16x8*)(Bbase + j * 16 * 128 + k0 * 32);
    const unsigned short* Abase = embb + (size_t)(mrow0 + m_) * 128 + q * 8;
    bf16x8 a0[4], a1[4];
#pragma unroll
    for (int k0 = 0; k0 < 4; k0++)
        a0[k0] = *(const bf16x8*)(Abase + k0 * 32);
#pragma unroll
    for (int t = 0; t < 16; t++) {
        int m0 = mrow0 + t * 16;
        unsigned short* tw = tile[t & 1];
        bf16x8* acur = (t & 1) ? a1 : a0;
        bf16x8* anext = (t & 1) ? a0 : a1;
        if (t < 15) {
#pragma unroll
            for (int k0 = 0; k0 < 4; k0++)
                anext[k0] = *(const bf16x8*)(Abase + (size_t)(t + 1) * 16 * 128 + k0 * 32);
        }
        f32x4 acc[4] = {};
#pragma unroll
        for (int k0 = 0; k0 < 4; k0++)
#pragma unroll
            for (int j = 0; j < 4; j++)
                acc[j] = __builtin_amdgcn_mfma_f32_16x16x32_bf16(B[j][k0], acur[k0], acc[j], 0, 0, 0);
        // pack: row m_, cols wave*64 + jj*16 + q*4 (+reg)
#pragma unroll
        for (int jj = 0; jj < 4; jj++) {
            uint2 s;
            s.x = cvt2(acc[jj][0], acc[jj][1]);
            s.y = cvt2(acc[jj][2], acc[jj][3]);
            *(uint2*)(tw + m_ * 260 + wave * 64 + jj * 16 + q * 4) = s;
        }
        __syncthreads();
        // merged store: 512 uint4 chunks (16 rows x 512B), 2 per thread
#pragma unroll
        for (int half = 0; half < 2; half++) {
            int idx = threadIdx.x + half * 256;
            int row = idx >> 5, c16 = idx & 31;
            uint4 v = *(const uint4*)(tw + row * 260 + c16 * 8);
            int grow = m0 + row;
            if (grow < N_NODES)
                *(uint4*)(xw + (size_t)grow * 1024 + bn4 * 256 + c16 * 8) = v;
        }
    }
}

// edge1csr: one wave per node, single pass (deg packed).  8 edges/instr.
__global__ __launch_bounds__(256) void edge1csr(const unsigned int* __restrict__ packed,
                                                const int* __restrict__ rowptr,
                                                const unsigned short* __restrict__ xw,
                                                const float* __restrict__ bias1,
                                                unsigned short* __restrict__ h1b) {
    __shared__ unsigned int ebuf[4 * 64];
    __shared__ float vbuf[4 * 64];
    int wave = threadIdx.x >> 6, lane = threadIdx.x & 63;
    int f = blockIdx.x * 4 + wave;
    if (f >= N_NODES) return;
    int s = rowptr[f], k = rowptr[f + 1] - s;
    int sub = lane & 7, p = lane >> 3;
    f32x4 acc = {0.f, 0.f, 0.f, 0.f};
    for (int base = 0; base < k; base += 64) {
        int e = base + lane;
        if (e < k) {
            unsigned int pk = packed[s + e];
            ebuf[wave * 64 + lane] = pk;
            vbuf[wave * 64 + lane] = 1.0f / (float)(pk >> 22);
        }
        int cnum = min(64, k - base);
        int nst = (cnum + 7) >> 3;
#pragma unroll 4
        for (int i = 0; i < nst; i++) {
            int ei = (i << 3) + p;
            if (ei < cnum) {
                unsigned int pk = ebuf[wave * 64 + ei];
                float v = vbuf[wave * 64 + ei];
                int t_ = pk & 0x1FFFF, r = (pk >> 17) & 31;
                ushort4 raw = *(const ushort4*)(xw + (size_t)t_ * 1024 + (r << 5) + (sub << 2));
                acc.x += v * b2f(raw.x); acc.y += v * b2f(raw.y);
                acc.z += v * b2f(raw.z); acc.w += v * b2f(raw.w);
            }
        }
    }
#pragma unroll
    for (int ofs = 8; ofs < 64; ofs <<= 1) {
        acc.x += __shfl_xor(acc.x, ofs, 64);
        acc.y += __shfl_xor(acc.y, ofs, 64);
        acc.z += __shfl_xor(acc.z, ofs, 64);
        acc.w += __shfl_xor(acc.w, ofs, 64);
    }
    if (p == 0) {
        int h = sub << 2;
        ushort4 o;
        o.x = f2b(fmaxf(acc.x + bias1[h + 0], 0.f));
        o.y = f2b(fmaxf(acc.y + bias1[h + 1], 0.f));
        o.z = f2b(fmaxf(acc.z + bias1[h + 2], 0.f));
        o.w = f2b(fmaxf(acc.w + bias1[h + 3], 0.f));
        *(ushort4*)(h1b + (size_t)f * 32 + h) = o;
    }
}

// GEMM2 (streaming-wave + LDS-pack epilogue, R11): z[m][j2] = sum_h h1b[m][h]*w2T[j2][h].
__global__ __launch_bounds__(256) void gemm2(const unsigned short* __restrict__ h1b,
                                             const unsigned short* __restrict__ w2T,
                                             unsigned short* __restrict__ z) {
    __shared__ unsigned short ldsT[4 * 16 * 136];
    int id = blockIdx.x;
    int xcd = id & 7, w = id >> 3;
    int bn = w & 7, mgl = w >> 3;
    int mg = mgl * 8 + xcd;
    if (mg >= 98) return;
    int lane = threadIdx.x & 63, wave = threadIdx.x >> 6;
    int m_ = lane & 15, q = lane >> 4;
    unsigned short* tw = &ldsT[wave * 16 * 136];
    bf16x8 B[4];
    const unsigned short* Bbase = w2T + (size_t)(bn * 64 + m_) * 32 + q * 8;
#pragma unroll
    for (int j = 0; j < 4; j++)
        B[j] = *(const bf16x8*)(Bbase + j * 16 * 32);
    int mrow0 = mg * 1024 + wave * 32;
    const unsigned short* Abase = h1b + (size_t)(mrow0 + m_) * 32 + q * 8;
    bf16x8 a0[2], a1[2];
    if (mrow0 < N_PAD) {
        a0[0] = *(const bf16x8*)(Abase);
        a0[1] = *(const bf16x8*)(Abase + 16 * 32);
    }
#pragma unroll
    for (int t = 0; t < 8; t++) {
        int m0 = mrow0 + t * 128;
        if (m0 >= N_PAD) break;
        bf16x8* acur = (t & 1) ? a1 : a0;
        bf16x8* anext = (t & 1) ? a0 : a1;
        if (t < 7 && m0 + 128 < N_PAD) {
            anext[0] = *(const bf16x8*)(Abase + (size_t)(t + 1) * 128 * 32);
            anext[1] = *(const bf16x8*)(Abase + (size_t)(t + 1) * 128 * 32 + 16 * 32);
        }
        f32x4 acc[2][4] = {};
#pragma unroll
        for (int i = 0; i < 2; i++)
#pragma unroll
            for (int j = 0; j < 4; j++)
                acc[i][j] = __builtin_amdgcn_mfma_f32_16x16x32_bf16(B[j], acur[i], acc[i][j], 0, 0, 0);
#pragma unroll
        for (int i = 0; i < 2; i++) {
#pragma unroll
            for (int jj = 0; jj < 4; jj++) {
                ushort4 s;
                s.x = f2b(acc[i][jj][0]); s.y = f2b(acc[i][jj][1]);
                s.z = f2b(acc[i][jj][2]); s.w = f2b(acc[i][jj][3]);
                *(ushort4*)(tw + m_ * 136 + jj * 16 + q * 4) = s;
            }
            __asm__ volatile("s_waitcnt lgkmcnt(0)" ::: "memory");
#pragma unroll
            for (int ri = 0; ri < 2; ri++) {
                int row = (lane >> 3) + ri * 8;
                int c = lane & 7;
                uint4 v = *(const uint4*)(tw + row * 136 + c * 8);
                int grow = m0 + i * 16 + row;
                if (grow < N_NODES)
                    *(uint4*)(z + (size_t)grow * 512 + bn * 64 + c * 8) = v;
            }
            __asm__ volatile("s_waitcnt lgkmcnt(0)" ::: "memory");
        }
    }
}

// edge2csr: one wave per node, single pass.  16 edges/instr, float4 store.
__global__ __launch_bounds__(256) void edge2csr(const unsigned int* __restrict__ packed,
                                                const int* __restrict__ rowptr,
                                                const unsigned short* __restrict__ z,
                                                const float* __restrict__ bias2,
                                                float* __restrict__ out) {
    __shared__ unsigned int ebuf[4 * 64];
    __shared__ float vbuf[4 * 64];
    int wave = threadIdx.x >> 6, lane = threadIdx.x & 63;
    int f = blockIdx.x * 4 + wave;
    if (f >= N_NODES) return;
    int s = rowptr[f], k = rowptr[f + 1] - s;
    int sub = lane & 3, p = lane >> 2;
    f32x4 acc = {0.f, 0.f, 0.f, 0.f};
    for (int base = 0; base < k; base += 64) {
        int e = base + lane;
        if (e < k) {
            unsigned int pk = packed[s + e];
            ebuf[wave * 64 + lane] = pk;
            vbuf[wave * 64 + lane] = 1.0f / (float)(pk >> 22);
        }
        int cnum = min(64, k - base);
        int nst = (cnum + 15) >> 4;
#pragma unroll 4
        for (int i = 0; i < nst; i++) {
            int ei = (i << 4) + p;
            if (ei < cnum) {
                unsigned int pk = ebuf[wave * 64 + ei];
                float v = vbuf[wave * 64 + ei];
                int t_ = pk & 0x1FFFF, r = (pk >> 17) & 31;
                ushort4 raw = *(const ushort4*)(z + (size_t)t_ * 512 + (r << 4) + (sub << 2));
                acc.x += v * b2f(raw.x); acc.y += v * b2f(raw.y);
                acc.z += v * b2f(raw.z); acc.w += v * b2f(raw.w);
            }
        }
    }
#pragma unroll
    for (int ofs = 4; ofs < 64; ofs <<= 1) {
        acc.x += __shfl_xor(acc.x, ofs, 64);
        acc.y += __shfl_xor(acc.y, ofs, 64);
        acc.z += __shfl_xor(acc.z, ofs, 64);
        acc.w += __shfl_xor(acc.w, ofs, 64);
    }
    if (p == 0) {
        int c = sub << 2;
        float4 o;
        o.x = acc.x + bias2[c + 0];
        o.y = acc.y + bias2[c + 1];
        o.z = acc.z + bias2[c + 2];
        o.w = acc.w + bias2[c + 3];
        *(float4*)(out + (size_t)f * 16 + c) = o;
    }
}

extern "C" void kernel_launch(void* const* d_in, const int* in_sizes, int n_in,
                              void* d_out, int out_size, void* d_ws, size_t ws_size,
                              hipStream_t stream) {
    (void)in_sizes; (void)n_in; (void)out_size; (void)ws_size;
    const float* emb    = (const float*)d_in[0];
    const float* comps1 = (const float*)d_in[1];
    const float* bases1 = (const float*)d_in[2];
    const float* comps2 = (const float*)d_in[3];
    const float* bases2 = (const float*)d_in[4];
    const float* bias1  = (const float*)d_in[5];
    const float* bias2  = (const float*)d_in[6];
    const int* rel = (const int*)d_in[7];
    const int* fr  = (const int*)d_in[8];
    const int* to  = (const int*)d_in[9];
    float* out = (float*)d_out;
    char* ws = (char*)d_ws;

    // workspace layout (bytes); total ~250.3 MB
    int* gCursor         = (int*)(ws);                        // 1,568
    int* bucketBase      = (int*)(ws + 2048);                 // 1,568
    int* rowptr          = (int*)(ws + 4096);                 // 401,412
    unsigned int* packed = (unsigned int*)(ws + 406528);      // 12,800,000
    unsigned short* h1b  = (unsigned short*)(ws + 13206528);  // 6,406,144 (N_PAD x 32)
    unsigned short* w1T  = (unsigned short*)(ws + 19612672);  // 262,144
    unsigned short* w2T  = (unsigned short*)(ws + 19874816);  // 32,768
    unsigned short* embb = (unsigned short*)(ws + 19907584);  // 25,624,576 (N_PAD x 128)
    unsigned short* xw   = (unsigned short*)(ws + 45532160);  // 204,800,000
    unsigned short* z    = xw;                 // alias: xw dead before gemm2
    unsigned int* stage  = (unsigned int*)xw;  // alias: stage dead before gemm1

    kcur<<<2, 256, 0, stream>>>(gCursor);
    kfront<<<NBIN + NEMB + NW1 + NW2, 256, 0, stream>>>(
        rel, fr, to, gCursor, stage, emb, embb,
        comps1, bases1, w1T, comps2, bases2, w2T);
    kscan<<<1, 512, 0, stream>>>(gCursor, bucketBase);
    kscatter2<<<NB, 256, 0, stream>>>(stage, gCursor, bucketBase, rowptr, packed);
    gemm1<<<1568, 256, 0, stream>>>(embb, w1T, xw);    // 8 xcd * 4 bn4 * 49 mgh
    edge1csr<<<25000, 256, 0, stream>>>(packed, rowptr, xw, bias1, h1b);
    gemm2<<<832, 256, 0, stream>>>(h1b, w2T, z);       // 8 xcd * 8 bn * 13 mgl
    edge2csr<<<25000, 256, 0, stream>>>(packed, rowptr, z, bias2, out);
}